// Round 13
// baseline (816.542 us; speedup 1.0000x reference)
//
#include <hip/hip_runtime.h>
#include <math.h>

#define NBATCH 8
#define NPTS   2048
#define NPOINT 512
#define KNB    16
#define NROWS  (NBATCH*NPOINT*KNB)   // 65536

typedef unsigned short ushort_t;
typedef unsigned int   uint_t;
typedef unsigned long long ull_t;
typedef __attribute__((ext_vector_type(8))) short  short8;   // 8 bf16 (4 VGPRs)
typedef __attribute__((ext_vector_type(4))) float  f32x4;    // MFMA C/D

// g_bankF element offsets (bf16, MFMA-fragment-major: [kc][nt][lane][8])
#define B0_OFF 0        // COUT=64,  K=512  -> 32768 elems
#define B1_OFF 32768    // COUT=128, K=512  -> 65536
#define B2_OFF 98304    // COUT=256, K=1024 -> 262144
#define BT_TOT 360448

// ---------------------------------------------------------------------------
// Scratch in static __device__ globals. Referenced ONLY in device code.
// ---------------------------------------------------------------------------
__device__ __align__(16) int      g_fidx[NBATCH * NPOINT];        //  16 KB
__device__ __align__(16) int      g_knn [NROWS];                  // 256 KB
__device__ __align__(16) float    g_sums[1024];                   //   4 KB
__device__ __align__(16) float    g_pT  [NBATCH * NPTS * 64];     //   4 MB
__device__ __align__(16) float    g_S   [(size_t)3 * NROWS * 8];  //   6 MB
__device__ __align__(16) float    g_act1[(size_t)NROWS * 64];     //  16 MB
__device__ __align__(16) float    g_act2[(size_t)NROWS * 128];    //  32 MB
__device__ __align__(16) ushort_t g_bankF[BT_TOT];                // 704 KB bf16 fragments

// f32 -> bf16 round-to-nearest-even (finite inputs).
__device__ __forceinline__ ushort_t f2bf(float f) {
    uint_t u = __float_as_uint(f);
    return (ushort_t)((u + 0x7FFFu + ((u >> 16) & 1u)) >> 16);
}

// DPP-shifted copy of a u64 key (bound_ctrl=1: invalid lanes read 0, the
// identity for unsigned max of our non-negative keys).
template<int CTRL>
__device__ __forceinline__ ull_t dpp_u64(ull_t k) {
    int lo = (int)(uint_t)k;
    int hi = (int)(uint_t)(k >> 32);
    int slo = __builtin_amdgcn_update_dpp(0, lo, CTRL, 0xF, 0xF, true);
    int shi = __builtin_amdgcn_update_dpp(0, hi, CTRL, 0xF, 0xF, true);
    return ((ull_t)(uint_t)shi << 32) | (uint_t)slo;
}

// Convert one bank element into fragment-major bf16 layout.
// e enumerates (kc, nt, lane, j); value = bank[k=kc*32+q*8+j][n=nt*16+nlo].
template<int COUT>
__device__ __forceinline__ void bank_frag(const float* __restrict__ bank,
                                          ushort_t* __restrict__ dst, int e) {
    const int j = e & 7;
    const int lane = (e >> 3) & 63;
    const int rem = e >> 9;
    constexpr int NTL = COUT / 16;
    const int nt = rem % NTL;
    const int kc = rem / NTL;
    const int q = lane >> 4, nlo = lane & 15;
    const int k = kc * 32 + q * 8 + j;
    const int n = nt * 16 + nlo;
    dst[e] = f2bf(bank[(size_t)k * COUT + n]);
}

// ---------------------------------------------------------------------------
// front_kernel: blocks 0-7 = FPS; 8-263 = transpose points; 264 = zero sums;
// 265-1672 = convert banks to bf16 fragment-major layout (hidden under FPS).
// FPS: DPP wave argmax; winning lane publishes {key, cx, cy, cz} in a parity
// slot; all threads read the 4 slots post-barrier and select centroid+index
// in registers. ONE barrier per iteration, no dependent LDS centroid read.
// ---------------------------------------------------------------------------
__global__ __launch_bounds__(256) void front_kernel(const float* __restrict__ xyz,
                                                    const float* __restrict__ points,
                                                    const float* __restrict__ bank0,
                                                    const float* __restrict__ bank1,
                                                    const float* __restrict__ bank2) {
    __shared__ float smem[3 * NPTS];
    __shared__ ull_t s_key[2][4];
    __shared__ float s_cx[2][4], s_cy[2][4], s_cz[2][4];
    const int bid = blockIdx.x;
    const int t = threadIdx.x;

    if (bid >= NBATCH) {
        if (bid < NBATCH + 256) {
            // ---- transpose points ----
            float (*tile)[65] = reinterpret_cast<float(*)[65]>(smem);
            const int blk = bid - NBATCH;
            const int b = blk >> 5;
            const int n0 = (blk & 31) * 64;
            const int lane = t & 63, q = t >> 6;
            #pragma unroll
            for (int i = 0; i < 16; ++i) {
                int c = q * 16 + i;
                tile[c][lane] = points[(b * 64 + c) * NPTS + n0 + lane];
            }
            __syncthreads();
            #pragma unroll
            for (int i = 0; i < 16; ++i) {
                int n = q * 16 + i;
                g_pT[(size_t)(b * NPTS + n0 + n) * 64 + lane] = tile[lane][n];
            }
        } else if (bid == NBATCH + 256) {
            // ---- zero BN-stats ----
            #pragma unroll
            for (int j = 0; j < 4; ++j) g_sums[j * 256 + t] = 0.0f;
        } else {
            // ---- bank -> fragment-major bf16 ----
            const int e = (bid - (NBATCH + 257)) * 256 + t;
            if (e < 32768) {
                bank_frag<64>(bank0, g_bankF + B0_OFF, e);
            } else if (e < 98304) {
                bank_frag<128>(bank1, g_bankF + B1_OFF, e - 32768);
            } else {
                bank_frag<256>(bank2, g_bankF + B2_OFF, e - 98304);
            }
        }
        return;
    }

    // ---- FPS ----
    {
        #pragma clang fp contract(off)
        const int b = bid;
        const int lane = t & 63, w4 = t >> 6;
        const float* xb = xyz + b * 3 * NPTS;
        float* s_x = smem;
        float* s_y = smem + NPTS;
        float* s_z = smem + 2 * NPTS;
        float x[8], y[8], z[8], d[8];
        #pragma unroll
        for (int j = 0; j < 8; ++j) {
            int p = j * 256 + t;
            float vx = xb[p], vy = xb[NPTS + p], vz = xb[2*NPTS + p];
            x[j] = vx; y[j] = vy; z[j] = vz;
            s_x[p] = vx; s_y[p] = vy; s_z[p] = vz;
            d[j] = 1e10f;
        }
        __syncthreads();
        int far = 0;
        float cx = s_x[0], cy = s_y[0], cz = s_z[0];
        for (int i = 0; i < NPOINT; ++i) {
            if (t == 0) g_fidx[b * NPOINT + i] = far;
            float best = -1.0f; int bi = 0;
            float bx = 0.f, by = 0.f, bz = 0.f;
            #pragma unroll
            for (int j = 0; j < 8; ++j) {
                float dx = x[j] - cx;
                float dy = y[j] - cy;
                float dz = z[j] - cz;
                float dd = dx*dx + dy*dy;   // ((dx^2+dy^2)+dz^2) like np
                dd = dd + dz*dz;
                float dn = fminf(d[j], dd);
                d[j] = dn;
                if (dn > best) { best = dn; bi = j * 256 + t; bx = x[j]; by = y[j]; bz = z[j]; }
            }
            ull_t key = (((ull_t)__float_as_uint(best)) << 32) | (uint_t)(~bi);
            ull_t rk = key;
            { ull_t s = dpp_u64<0x111>(rk); if (s > rk) rk = s; }  // row_shr:1
            { ull_t s = dpp_u64<0x112>(rk); if (s > rk) rk = s; }  // row_shr:2
            { ull_t s = dpp_u64<0x114>(rk); if (s > rk) rk = s; }  // row_shr:4
            { ull_t s = dpp_u64<0x118>(rk); if (s > rk) rk = s; }  // row_shr:8
            { ull_t s = dpp_u64<0x142>(rk); if (s > rk) rk = s; }  // row_bcast:15
            { ull_t s = dpp_u64<0x143>(rk); if (s > rk) rk = s; }  // row_bcast:31
            uint_t wlo = (uint_t)__builtin_amdgcn_readlane((int)(uint_t)rk, 63);
            uint_t whi = (uint_t)__builtin_amdgcn_readlane((int)(uint_t)(rk >> 32), 63);
            ull_t wavekey = ((ull_t)whi << 32) | wlo;
            const int par = i & 1;
            if (key == wavekey) {   // unique winner lane in this wave
                s_key[par][w4] = key;
                s_cx[par][w4] = bx; s_cy[par][w4] = by; s_cz[par][w4] = bz;
            }
            __syncthreads();
            ull_t k0 = s_key[par][0], k1 = s_key[par][1];
            ull_t k2 = s_key[par][2], k3 = s_key[par][3];
            float x0 = s_cx[par][0], x1 = s_cx[par][1], x2 = s_cx[par][2], x3 = s_cx[par][3];
            float y0 = s_cy[par][0], y1 = s_cy[par][1], y2 = s_cy[par][2], y3 = s_cy[par][3];
            float z0 = s_cz[par][0], z1 = s_cz[par][1], z2 = s_cz[par][2], z3 = s_cz[par][3];
            if (k1 > k0) { k0 = k1; x0 = x1; y0 = y1; z0 = z1; }
            if (k3 > k2) { k2 = k3; x2 = x3; y2 = y3; z2 = z3; }
            if (k2 > k0) { k0 = k2; x0 = x2; y0 = y2; z0 = z2; }
            far = (int)(~(uint_t)k0) & (NPTS - 1);
            cx = x0; cy = y0; cz = z0;
        }
    }
}

// ---------------------------------------------------------------------------
// KNN: one wave per query. Expanded |a|^2+|b|^2-2ab form (contract off);
// 16 rounds of wave-min with index tie-break.
// ---------------------------------------------------------------------------
__global__ __launch_bounds__(256) void knn_kernel(const float* __restrict__ xyz) {
    #pragma clang fp contract(off)
    const int wave = blockIdx.x * 4 + (threadIdx.x >> 6);
    const int lane = threadIdx.x & 63;
    const int b = wave >> 9;
    const float* xb = xyz + b * 3 * NPTS;
    const int fi = g_fidx[wave] & (NPTS - 1);
    float ax = xb[fi];
    float ay = xb[NPTS + fi];
    float az = xb[2*NPTS + fi];
    float sa = ax*ax + ay*ay; sa = sa + az*az;
    float d[32];
    #pragma unroll
    for (int j = 0; j < 32; ++j) {
        int p = j * 64 + lane;
        float bx = xb[p];
        float by = xb[NPTS + p];
        float bz = xb[2*NPTS + p];
        float sb = bx*bx + by*by; sb = sb + bz*bz;
        float dot = ax*bx + ay*by; dot = dot + az*bz;
        float t1 = sa + sb;
        float t2 = 2.0f * dot;
        d[j] = t1 - t2;
    }
    for (int r = 0; r < KNB; ++r) {
        float best = 1e30f; int bi = 0x7fffffff;
        #pragma unroll
        for (int j = 0; j < 32; ++j) {
            if (d[j] < best) { best = d[j]; bi = j * 64 + lane; }
        }
        #pragma unroll
        for (int m = 32; m >= 1; m >>= 1) {
            float ov = __shfl_xor(best, m);
            int   oi = __shfl_xor(bi, m);
            if (ov < best || (ov == best && oi < bi)) { best = ov; bi = oi; }
        }
        bi &= (NPTS - 1);
        if (lane == 0) g_knn[wave * KNB + r] = bi;
        int rl = bi & 63, rs = bi >> 6;
        if (lane == rl) {
            #pragma unroll
            for (int j = 0; j < 32; ++j) if (j == rs) d[j] = 1e30f;
        }
    }
}

// ---------------------------------------------------------------------------
// score3_kernel: blocks 0-255 compute geometry ONCE and all THREE scoring
// MLPs; blocks 256-271 do the small gathered outputs.
// ---------------------------------------------------------------------------
__global__ __launch_bounds__(256) void score3_kernel(
    const float* __restrict__ xyz, const float* __restrict__ nrm,
    const float* __restrict__ Xa, const float* __restrict__ Ya,
    const float* __restrict__ w1_0, const float* __restrict__ b1_0,
    const float* __restrict__ w2_0, const float* __restrict__ b2_0,
    const float* __restrict__ w1_1, const float* __restrict__ b1_1,
    const float* __restrict__ w2_1, const float* __restrict__ b2_1,
    const float* __restrict__ w1_2, const float* __restrict__ b1_2,
    const float* __restrict__ w2_2, const float* __restrict__ b2_2,
    float* __restrict__ out) {
    const int bid = blockIdx.x;
    const int t = threadIdx.x;
    if (bid >= 256) {
        const int g = (bid - 256) * 256 + t;       // b*512+p
        const int b = g / NPOINT, p = g % NPOINT;
        const int fi = g_fidx[g] & (NPTS - 1);
        const int n0 = g_knn[g * KNB] & (NPTS - 1);
        #pragma unroll
        for (int a = 0; a < 3; ++a) {
            out[            (b*3 + a) * NPOINT + p] = xyz[(b*3 + a) * NPTS + fi];
            out[12288 +     (b*3 + a) * NPOINT + p] = nrm[(b*3 + a) * NPTS + n0];
            out[24576 +     (b*3 + a) * NPOINT + p] = Xa [(b*3 + a) * NPTS + n0];
            out[36864 +     (b*3 + a) * NPOINT + p] = Ya [(b*3 + a) * NPTS + n0];
        }
        return;
    }
    __shared__ float w1s[3][16][10];
    __shared__ float b1s[3][16];
    __shared__ float w2s[3][8][16];
    __shared__ float b2s[3][8];
    {
        const float* w1p[3] = {w1_0, w1_1, w1_2};
        const float* b1p[3] = {b1_0, b1_1, b1_2};
        const float* w2p[3] = {w2_0, w2_1, w2_2};
        const float* b2p[3] = {b2_0, b2_1, b2_2};
        #pragma unroll
        for (int l = 0; l < 3; ++l) {
            if (t < 160) w1s[l][t / 10][t % 10] = w1p[l][t];
            if (t < 16)  b1s[l][t] = b1p[l][t];
            if (t < 128) w2s[l][t / 16][t % 16] = w2p[l][t];
            if (t < 8)   b2s[l][t] = b2p[l][t];
        }
    }
    __syncthreads();
    const int row = bid * 256 + t;
    const int b = row >> 13;
    const int p = (row >> 4) & 511;
    const int n = g_knn[row] & (NPTS - 1);
    const int fi = g_fidx[b * NPOINT + p] & (NPTS - 1);
    const float* xb = xyz + b * 3 * NPTS;
    const float* nb = nrm + b * 3 * NPTS;
    const float* Xb = Xa  + b * 3 * NPTS;
    const float* Yb = Ya  + b * 3 * NPTS;
    float gx, gy, gz, sq, draw, nnv;
    {
        #pragma clang fp contract(off)
        gx = xb[n]        - xb[fi];
        gy = xb[NPTS + n] - xb[NPTS + fi];
        gz = xb[2*NPTS+n] - xb[2*NPTS+fi];
        sq = gx*gx + gy*gy;
        sq = sq + gz*gz;
        draw = sqrtf(sq + 1e-10f);
        nnv = sqrtf(sq);
    }
    float dmin = draw, dmax = draw;
    #pragma unroll
    for (int m = 1; m < 16; m <<= 1) {
        dmin = fminf(dmin, __shfl_xor(dmin, m, 16));
        dmax = fmaxf(dmax, __shfl_xor(dmax, m, 16));
    }
    float dist;
    {
        #pragma clang fp contract(off)
        dist = (draw - dmin) / ((dmax - dmin) + 1e-10f);
    }
    float nx = nb[n], ny = nb[NPTS+n], nz = nb[2*NPTS+n];
    float Xx = Xb[n], Xy = Xb[NPTS+n], Xz = Xb[2*NPTS+n];
    float Yx = Yb[n], Yy = Yb[NPTS+n], Yz = Yb[2*NPTS+n];
    float g[10];
    g[0]=gx; g[1]=gy; g[2]=gz; g[3]=dist; g[4]=nx; g[5]=ny; g[6]=nz;
    {
        float vs[3][3] = {{nx,ny,nz},{Xx,Xy,Xz},{Yx,Yy,Yz}};
        #pragma unroll
        for (int a = 0; a < 3; ++a) {
            float vx=vs[a][0], vy=vs[a][1], vz=vs[a][2];
            float dot, nv;
            {
                #pragma clang fp contract(off)
                dot = gx*vx + gy*vy; dot = dot + gz*vz;
                float s2 = vx*vx + vy*vy; s2 = s2 + vz*vz;
                nv = sqrtf(s2);
            }
            float cc = dot / (nnv * nv + 1e-8f);
            cc = fminf(1.0f, fmaxf(-1.0f, cc));
            g[7+a] = acosf(cc) / 3.14159274101257324f;
        }
    }
    #pragma unroll
    for (int l = 0; l < 3; ++l) {
        float h[16];
        #pragma unroll
        for (int i = 0; i < 16; ++i) {
            float a = b1s[l][i];
            #pragma unroll
            for (int j = 0; j < 10; ++j) a += w1s[l][i][j] * g[j];
            h[i] = fmaxf(a, 0.0f);
        }
        float e[8]; float mx = -1e30f;
        #pragma unroll
        for (int m = 0; m < 8; ++m) {
            float a = b2s[l][m];
            #pragma unroll
            for (int j = 0; j < 16; ++j) a += w2s[l][m][j] * h[j];
            e[m] = a; mx = fmaxf(mx, a);
        }
        float sum = 0.0f;
        #pragma unroll
        for (int m = 0; m < 8; ++m) { e[m] = expf(e[m] - mx); sum += e[m]; }
        #pragma unroll
        for (int m = 0; m < 8; ++m)
            g_S[(size_t)l * NROWS * 8 + (size_t)row * 8 + m] = e[m] / sum;
    }
}

// ---------------------------------------------------------------------------
// MFMA PAConv GEMM v5 — BARRIER-FREE K-loop:
// wave w stages A-rows [16w,16w+16) (threads t in [64w,64w+64) have
// arow_i = t>>2 in that range) and reads ONLY those rows -> the As LDS is
// wave-local, so no __syncthreads is needed between staging and MFMA.
// Same-wave LDS ordering is program order (compiler inserts lgkmcnt).
//  - B fragments: one coalesced 16B/lane load from fragment-major g_bankF.
//  - c0 outer / m inner: A row loaded+BN'd once per c-chunk (regs).
//  - LAYER>=1 staging applies previous BN+relu; LAYER<2 epilogue accumulates
//    per-channel sum/sumsq into g_sums (its own barrier, kept).
// ---------------------------------------------------------------------------
template<int LAYER, int CIN, int COUT>
__global__ __launch_bounds__(256) void gemm_kernel(const float* __restrict__ gamma,
                                                   const float* __restrict__ beta,
                                                   float* __restrict__ dout) {
    const float* __restrict__ A = (LAYER == 0) ? g_pT : (LAYER == 1) ? g_act1 : g_act2;
    float* __restrict__ O = (LAYER == 0) ? g_act1 : (LAYER == 1) ? g_act2 : dout;
    constexpr int NT = COUT / 16;
    constexpr int BOFF = (LAYER == 0) ? B0_OFF : (LAYER == 1) ? B1_OFF : B2_OFF;
    __shared__ ushort_t As[2][64][36];
    __shared__ float s_scale[(LAYER >= 1) ? CIN : 1];
    __shared__ float s_shift[(LAYER >= 1) ? CIN : 1];
    __shared__ float s_red[(LAYER < 2) ? 2 : 1][(LAYER < 2) ? 4 : 1][(LAYER < 2) ? COUT : 1];

    const int t = threadIdx.x;
    const int lane = t & 63, w = t >> 6;
    const int q = lane >> 4, nlo = lane & 15;
    const int row0 = blockIdx.x * 64;
    const int arow_i = t >> 2, acg = t & 3;

    if constexpr (LAYER >= 1) {
        const float* sb = (LAYER == 1) ? g_sums : (g_sums + 256);
        if (t < CIN) {
            float mu  = sb[t] * (1.0f / 65536.0f);
            float var = sb[CIN + t] * (1.0f / 65536.0f) - mu * mu;
            var = fmaxf(var, 0.0f);
            float sc = gamma[t] / sqrtf(var + 1e-5f);
            s_scale[t] = sc;
            s_shift[t] = beta[t] - mu * sc;
        }
        __syncthreads();   // s_scale/s_shift are cross-wave: keep this one
    }

    size_t arow;
    if (LAYER == 0) {
        const int row = row0 + arow_i;
        const int b = row >> 13;
        const int n = g_knn[row] & (NPTS - 1);
        arow = (size_t)(b * NPTS + n) * 64;
    } else {
        arow = (size_t)(row0 + arow_i) * CIN;
    }
    const float* Sbase = g_S + (size_t)LAYER * NROWS * 8 + (size_t)(row0 + arow_i) * 8;

    float svv[8];
    #pragma unroll
    for (int m = 0; m < 8; ++m) svv[m] = Sbase[m];

    f32x4 acc[NT];
    #pragma unroll
    for (int i = 0; i < NT; ++i) acc[i] = (f32x4){0.f, 0.f, 0.f, 0.f};

    // fragment base for this lane: chunk kc, tile nt -> + (kc*NT + nt)*512
    const ushort_t* fbase = g_bankF + BOFF + lane * 8;

    int par = 0;
    for (int c0 = 0; c0 < CIN; c0 += 32) {
        // ---- load F chunk once, BN+relu once ----
        float v[8];
        {
            const float* ap = A + arow + c0 + acg * 8;
            float4 fa = *reinterpret_cast<const float4*>(ap);
            float4 fb = *reinterpret_cast<const float4*>(ap + 4);
            v[0]=fa.x; v[1]=fa.y; v[2]=fa.z; v[3]=fa.w;
            v[4]=fb.x; v[5]=fb.y; v[6]=fb.z; v[7]=fb.w;
            if constexpr (LAYER >= 1) {
                const int c = c0 + acg * 8;
                #pragma unroll
                for (int j = 0; j < 8; ++j)
                    v[j] = fmaxf(v[j] * s_scale[c + j] + s_shift[c + j], 0.f);
            }
        }
        for (int m = 0; m < 8; ++m) {
            // ---- stage A (sv[m]*F -> bf16) into wave-local parity buffer ----
            {
                const float sv = svv[m];
                uint_t* dst = reinterpret_cast<uint_t*>(&As[par][arow_i][acg * 8]);
                #pragma unroll
                for (int j = 0; j < 8; j += 2)
                    dst[j >> 1] = (uint_t)f2bf(sv * v[j]) | ((uint_t)f2bf(sv * v[j+1]) << 16);
            }
            // NO barrier: As rows [16w,16w+16) written and read by wave w only.
            // ---- MFMA: A from LDS, B coalesced from g_bankF ----
            union FragU { uint2 u2[2]; short8 s; } af;
            af.u2[0] = *reinterpret_cast<const uint2*>(&As[par][w*16 + nlo][q*8]);
            af.u2[1] = *reinterpret_cast<const uint2*>(&As[par][w*16 + nlo][q*8 + 4]);
            const int kc = m * (CIN / 32) + (c0 >> 5);
            const ushort_t* bk = fbase + (size_t)(kc * NT) * 512;
            #pragma unroll
            for (int nt = 0; nt < NT; ++nt) {
                FragU bf;
                bf.u2[0] = *reinterpret_cast<const uint2*>(bk + (size_t)nt * 512);
                bf.u2[1] = *reinterpret_cast<const uint2*>(bk + (size_t)nt * 512 + 4);
                acc[nt] = __builtin_amdgcn_mfma_f32_16x16x32_bf16(af.s, bf.s, acc[nt], 0, 0, 0);
            }
            par ^= 1;
        }
    }

    if constexpr (LAYER == 2) {
        // wave w holds rows w*16..w*16+15 = all K=16 neighbors of one (b,p)
        const int bp = (row0 >> 4) + w;
        const int b = bp >> 9, p = bp & 511;
        #pragma unroll
        for (int nt = 0; nt < NT; ++nt) {
            float mv = fmaxf(fmaxf(acc[nt][0], acc[nt][1]), fmaxf(acc[nt][2], acc[nt][3]));
            mv = fmaxf(mv, __shfl_xor(mv, 16));
            mv = fmaxf(mv, __shfl_xor(mv, 32));
            if (lane < 16)
                O[(size_t)(b * 256 + nt*16 + nlo) * NPOINT + p] = mv;
        }
    } else {
        // raw output + fused per-channel sum/sumsq
        #pragma unroll
        for (int nt = 0; nt < NT; ++nt)
            #pragma unroll
            for (int r2 = 0; r2 < 4; ++r2)
                O[(size_t)(row0 + w*16 + q*4 + r2) * COUT + nt*16 + nlo] = acc[nt][r2];
        #pragma unroll
        for (int nt = 0; nt < NT; ++nt) {
            float s  = acc[nt][0] + acc[nt][1] + acc[nt][2] + acc[nt][3];
            float ss = acc[nt][0]*acc[nt][0] + acc[nt][1]*acc[nt][1]
                     + acc[nt][2]*acc[nt][2] + acc[nt][3]*acc[nt][3];
            s  += __shfl_xor(s, 16);  s  += __shfl_xor(s, 32);
            ss += __shfl_xor(ss, 16); ss += __shfl_xor(ss, 32);
            if (q == 0) {
                s_red[0][w][nt*16 + nlo] = s;
                s_red[1][w][nt*16 + nlo] = ss;
            }
        }
        __syncthreads();
        if (t < COUT) {
            float s  = s_red[0][0][t] + s_red[0][1][t] + s_red[0][2][t] + s_red[0][3][t];
            float ss = s_red[1][0][t] + s_red[1][1][t] + s_red[1][2][t] + s_red[1][3][t];
            float* sb = (LAYER == 0) ? g_sums : (g_sums + 256);
            atomicAdd(&sb[t], s);
            atomicAdd(&sb[COUT + t], ss);
        }
    }
}

// ---------------------------------------------------------------------------
extern "C" void kernel_launch(void* const* d_in, const int* in_sizes, int n_in,
                              void* d_out, int out_size, void* d_ws, size_t ws_size,
                              hipStream_t stream) {
    const float* xyz    = (const float*)d_in[0];
    const float* nrm    = (const float*)d_in[1];
    const float* Xa     = (const float*)d_in[2];
    const float* Ya     = (const float*)d_in[3];
    const float* points = (const float*)d_in[4];
    const float* w1_0 = (const float*)d_in[5];  const float* b1_0 = (const float*)d_in[6];
    const float* w2_0 = (const float*)d_in[7];  const float* b2_0 = (const float*)d_in[8];
    const float* bank0 = (const float*)d_in[9];
    const float* g0 = (const float*)d_in[10];   const float* be0 = (const float*)d_in[11];
    const float* w1_1 = (const float*)d_in[12]; const float* b1_1 = (const float*)d_in[13];
    const float* w2_1 = (const float*)d_in[14]; const float* b2_1 = (const float*)d_in[15];
    const float* bank1 = (const float*)d_in[16];
    const float* g1 = (const float*)d_in[17];   const float* be1 = (const float*)d_in[18];
    const float* w1_2 = (const float*)d_in[19]; const float* b1_2 = (const float*)d_in[20];
    const float* w2_2 = (const float*)d_in[21]; const float* b2_2 = (const float*)d_in[22];
    const float* bank2 = (const float*)d_in[23];
    float* out = (float*)d_out;
    (void)d_ws; (void)ws_size; (void)in_sizes; (void)n_in; (void)out_size;

    // fps (0-7) + transpose (8-263) + zero sums (264) + bank frag conv (265-1672)
    front_kernel<<<1673, 256, 0, stream>>>(xyz, points, bank0, bank1, bank2);
    knn_kernel<<<1024, 256, 0, stream>>>(xyz);
    // geometry + all 3 score MLPs (0-255) + small outputs (256-271)
    score3_kernel<<<272, 256, 0, stream>>>(xyz, nrm, Xa, Ya,
                                           w1_0, b1_0, w2_0, b2_0,
                                           w1_1, b1_1, w2_1, b2_1,
                                           w1_2, b1_2, w2_2, b2_2, out);
    // layer 0: gather+GEMM -> raw act1 + BN stats
    gemm_kernel<0, 64, 64><<<1024, 256, 0, stream>>>(nullptr, nullptr, nullptr);
    // layer 1: BN0+relu fused in staging -> raw act2 + BN stats
    gemm_kernel<1, 64, 128><<<1024, 256, 0, stream>>>(g0, be0, nullptr);
    // layer 2: BN1+relu fused in staging -> fused max-k + transpose to d_out
    gemm_kernel<2, 128, 256><<<1024, 256, 0, stream>>>(g1, be1, out + 49152);
}

// Round 14
// 615.095 us; speedup vs baseline: 1.3275x; 1.3275x over previous
//
#include <hip/hip_runtime.h>
#include <math.h>

#define NBATCH 8
#define NPTS   2048
#define NPOINT 512
#define KNB    16
#define NROWS  (NBATCH*NPOINT*KNB)   // 65536

typedef unsigned short ushort_t;
typedef unsigned int   uint_t;
typedef unsigned long long ull_t;
typedef __attribute__((ext_vector_type(8))) short  short8;   // 8 bf16 (4 VGPRs)
typedef __attribute__((ext_vector_type(4))) float  f32x4;    // MFMA C/D

// g_bankF element offsets (bf16, MFMA-fragment-major: [kc][nt][lane][8])
#define B0_OFF 0        // COUT=64,  K=512  -> 32768 elems
#define B1_OFF 32768    // COUT=128, K=512  -> 65536
#define B2_OFF 98304    // COUT=256, K=1024 -> 262144
#define BT_TOT 360448

// LDS-only workgroup barrier: orders LDS ops across waves WITHOUT draining
// vmcnt, so global (B-fragment) loads stay in flight across K-steps.
#define LDS_BARRIER() asm volatile("s_waitcnt lgkmcnt(0)\n\ts_barrier" ::: "memory")

// ---------------------------------------------------------------------------
// Scratch in static __device__ globals. Referenced ONLY in device code.
// ---------------------------------------------------------------------------
__device__ __align__(16) int      g_fidx[NBATCH * NPOINT];        //  16 KB
__device__ __align__(16) int      g_knn [NROWS];                  // 256 KB
__device__ __align__(16) float    g_sums[1024];                   //   4 KB
__device__ __align__(16) float    g_pT  [NBATCH * NPTS * 64];     //   4 MB
__device__ __align__(16) float    g_S   [(size_t)3 * NROWS * 8];  //   6 MB
__device__ __align__(16) float    g_act1[(size_t)NROWS * 64];     //  16 MB
__device__ __align__(16) float    g_act2[(size_t)NROWS * 128];    //  32 MB
__device__ __align__(16) ushort_t g_bankF[BT_TOT];                // 704 KB bf16 fragments

// f32 -> bf16 round-to-nearest-even (finite inputs).
__device__ __forceinline__ ushort_t f2bf(float f) {
    uint_t u = __float_as_uint(f);
    return (ushort_t)((u + 0x7FFFu + ((u >> 16) & 1u)) >> 16);
}

// DPP-shifted copy of a u64 key (bound_ctrl=1: invalid lanes read 0, the
// identity for unsigned max of our keys).
template<int CTRL>
__device__ __forceinline__ ull_t dpp_u64(ull_t k) {
    int lo = (int)(uint_t)k;
    int hi = (int)(uint_t)(k >> 32);
    int slo = __builtin_amdgcn_update_dpp(0, lo, CTRL, 0xF, 0xF, true);
    int shi = __builtin_amdgcn_update_dpp(0, hi, CTRL, 0xF, 0xF, true);
    return ((ull_t)(uint_t)shi << 32) | (uint_t)slo;
}

__device__ __forceinline__ ull_t dpp_max_u64(ull_t key) {
    { ull_t s = dpp_u64<0x111>(key); if (s > key) key = s; }  // row_shr:1
    { ull_t s = dpp_u64<0x112>(key); if (s > key) key = s; }  // row_shr:2
    { ull_t s = dpp_u64<0x114>(key); if (s > key) key = s; }  // row_shr:4
    { ull_t s = dpp_u64<0x118>(key); if (s > key) key = s; }  // row_shr:8
    { ull_t s = dpp_u64<0x142>(key); if (s > key) key = s; }  // row_bcast:15
    { ull_t s = dpp_u64<0x143>(key); if (s > key) key = s; }  // row_bcast:31
    return key;   // wave max in lane 63
}

// Convert one bank element into fragment-major bf16 layout.
// e enumerates (kc, nt, lane, j); value = bank[k=kc*32+q*8+j][n=nt*16+nlo].
template<int COUT>
__device__ __forceinline__ void bank_frag(const float* __restrict__ bank,
                                          ushort_t* __restrict__ dst, int e) {
    const int j = e & 7;
    const int lane = (e >> 3) & 63;
    const int rem = e >> 9;
    constexpr int NTL = COUT / 16;
    const int nt = rem % NTL;
    const int kc = rem / NTL;
    const int q = lane >> 4, nlo = lane & 15;
    const int k = kc * 32 + q * 8 + j;
    const int n = nt * 16 + nlo;
    dst[e] = f2bf(bank[(size_t)k * COUT + n]);
}

// ---------------------------------------------------------------------------
// front_kernel: blocks 0-7 = FPS; 8-263 = transpose points; 264 = zero sums;
// 265-1672 = convert banks to bf16 fragment-major layout (hidden under FPS).
// FPS (r12-verbatim): DPP wave argmax -> lane 63, packed key
// (f32bits(dist)<<32)|~idx, parity-buffered s_key, 1 barrier/iter.
// ---------------------------------------------------------------------------
__global__ __launch_bounds__(256) void front_kernel(const float* __restrict__ xyz,
                                                    const float* __restrict__ points,
                                                    const float* __restrict__ bank0,
                                                    const float* __restrict__ bank1,
                                                    const float* __restrict__ bank2) {
    __shared__ float smem[3 * NPTS + 16];
    const int bid = blockIdx.x;
    const int t = threadIdx.x;

    if (bid >= NBATCH) {
        if (bid < NBATCH + 256) {
            // ---- transpose points ----
            float (*tile)[65] = reinterpret_cast<float(*)[65]>(smem);
            const int blk = bid - NBATCH;
            const int b = blk >> 5;
            const int n0 = (blk & 31) * 64;
            const int lane = t & 63, q = t >> 6;
            #pragma unroll
            for (int i = 0; i < 16; ++i) {
                int c = q * 16 + i;
                tile[c][lane] = points[(b * 64 + c) * NPTS + n0 + lane];
            }
            __syncthreads();
            #pragma unroll
            for (int i = 0; i < 16; ++i) {
                int n = q * 16 + i;
                g_pT[(size_t)(b * NPTS + n0 + n) * 64 + lane] = tile[lane][n];
            }
        } else if (bid == NBATCH + 256) {
            // ---- zero BN-stats ----
            #pragma unroll
            for (int j = 0; j < 4; ++j) g_sums[j * 256 + t] = 0.0f;
        } else {
            // ---- bank -> fragment-major bf16 ----
            const int e = (bid - (NBATCH + 257)) * 256 + t;
            if (e < 32768) {
                bank_frag<64>(bank0, g_bankF + B0_OFF, e);
            } else if (e < 98304) {
                bank_frag<128>(bank1, g_bankF + B1_OFF, e - 32768);
            } else {
                bank_frag<256>(bank2, g_bankF + B2_OFF, e - 98304);
            }
        }
        return;
    }

    // ---- FPS ----
    {
        #pragma clang fp contract(off)
        const int b = bid;
        const int lane = t & 63, w4 = t >> 6;
        const float* xb = xyz + b * 3 * NPTS;
        float* s_x = smem;
        float* s_y = smem + NPTS;
        float* s_z = smem + 2 * NPTS;
        ull_t* s_key = reinterpret_cast<ull_t*>(smem + 3 * NPTS);  // 8 slots
        float x[8], y[8], z[8], d[8];
        #pragma unroll
        for (int j = 0; j < 8; ++j) {
            int p = j * 256 + t;
            float vx = xb[p], vy = xb[NPTS + p], vz = xb[2*NPTS + p];
            x[j] = vx; y[j] = vy; z[j] = vz;
            s_x[p] = vx; s_y[p] = vy; s_z[p] = vz;
            d[j] = 1e10f;
        }
        __syncthreads();
        int far = 0;
        for (int i = 0; i < NPOINT; ++i) {
            if (t == 0) g_fidx[b * NPOINT + i] = far;
            float cx = s_x[far], cy = s_y[far], cz = s_z[far];
            float best = -1.0f; int bi = 0;
            #pragma unroll
            for (int j = 0; j < 8; ++j) {
                float dx = x[j] - cx;
                float dy = y[j] - cy;
                float dz = z[j] - cz;
                float dd = dx*dx + dy*dy;   // ((dx^2+dy^2)+dz^2) like np
                dd = dd + dz*dz;
                float dn = fminf(d[j], dd);
                d[j] = dn;
                if (dn > best) { best = dn; bi = j * 256 + t; }  // strict >
            }
            ull_t key = (((ull_t)__float_as_uint(best)) << 32) | (uint_t)(~bi);
            key = dpp_max_u64(key);
            uint_t wlo = (uint_t)__builtin_amdgcn_readlane((int)(uint_t)key, 63);
            uint_t whi = (uint_t)__builtin_amdgcn_readlane((int)(uint_t)(key >> 32), 63);
            if (lane == 0) s_key[((i & 1) << 2) + w4] = ((ull_t)whi << 32) | wlo;
            __syncthreads();
            const ull_t* kb = s_key + ((i & 1) << 2);
            ull_t k0 = kb[0], k1 = kb[1], k2 = kb[2], k3 = kb[3];
            if (k1 > k0) k0 = k1;
            if (k3 > k2) k2 = k3;
            if (k2 > k0) k0 = k2;
            far = (int)(~(uint_t)k0) & (NPTS - 1);
        }
    }
}

// ---------------------------------------------------------------------------
// KNN: one wave per query. Expanded |a|^2+|b|^2-2ab form (contract off).
// Wave argmin via u64 key DPP max-reduce: u = ascending-order map of f32
// bits (handles the tiny-negative fp case), key = (~u<<32)|(~idx) so max key
// = min dist, ties -> min idx (exactly the old butterfly semantics). d is
// never -0 (t1-t2 yields +0 on equality), so +/-0 ambiguity can't arise.
// ---------------------------------------------------------------------------
__global__ __launch_bounds__(256) void knn_kernel(const float* __restrict__ xyz) {
    #pragma clang fp contract(off)
    const int wave = blockIdx.x * 4 + (threadIdx.x >> 6);
    const int lane = threadIdx.x & 63;
    const int b = wave >> 9;
    const float* xb = xyz + b * 3 * NPTS;
    const int fi = g_fidx[wave] & (NPTS - 1);
    float ax = xb[fi];
    float ay = xb[NPTS + fi];
    float az = xb[2*NPTS + fi];
    float sa = ax*ax + ay*ay; sa = sa + az*az;
    float d[32];
    #pragma unroll
    for (int j = 0; j < 32; ++j) {
        int p = j * 64 + lane;
        float bx = xb[p];
        float by = xb[NPTS + p];
        float bz = xb[2*NPTS + p];
        float sb = bx*bx + by*by; sb = sb + bz*bz;
        float dot = ax*bx + ay*by; dot = dot + az*bz;
        float t1 = sa + sb;
        float t2 = 2.0f * dot;
        d[j] = t1 - t2;
    }
    for (int r = 0; r < KNB; ++r) {
        float best = 1e30f; int bi = 0x7fffffff;
        #pragma unroll
        for (int j = 0; j < 32; ++j) {
            if (d[j] < best) { best = d[j]; bi = j * 64 + lane; }
        }
        uint_t ub = __float_as_uint(best);
        ub = (ub & 0x80000000u) ? ~ub : (ub | 0x80000000u);   // ascending map
        ull_t key = ((ull_t)(~ub) << 32) | (uint_t)(~bi);
        key = dpp_max_u64(key);
        uint_t wlo = (uint_t)__builtin_amdgcn_readlane((int)(uint_t)key, 63);
        bi = (int)(~wlo) & (NPTS - 1);
        if (lane == 0) g_knn[wave * KNB + r] = bi;
        int rl = bi & 63, rs = bi >> 6;
        if (lane == rl) {
            #pragma unroll
            for (int j = 0; j < 32; ++j) if (j == rs) d[j] = 1e30f;
        }
    }
}

// ---------------------------------------------------------------------------
// score3_kernel: blocks 0-255 compute geometry ONCE and all THREE scoring
// MLPs; blocks 256-271 do the small gathered outputs.
// ---------------------------------------------------------------------------
__global__ __launch_bounds__(256) void score3_kernel(
    const float* __restrict__ xyz, const float* __restrict__ nrm,
    const float* __restrict__ Xa, const float* __restrict__ Ya,
    const float* __restrict__ w1_0, const float* __restrict__ b1_0,
    const float* __restrict__ w2_0, const float* __restrict__ b2_0,
    const float* __restrict__ w1_1, const float* __restrict__ b1_1,
    const float* __restrict__ w2_1, const float* __restrict__ b2_1,
    const float* __restrict__ w1_2, const float* __restrict__ b1_2,
    const float* __restrict__ w2_2, const float* __restrict__ b2_2,
    float* __restrict__ out) {
    const int bid = blockIdx.x;
    const int t = threadIdx.x;
    if (bid >= 256) {
        const int g = (bid - 256) * 256 + t;       // b*512+p
        const int b = g / NPOINT, p = g % NPOINT;
        const int fi = g_fidx[g] & (NPTS - 1);
        const int n0 = g_knn[g * KNB] & (NPTS - 1);
        #pragma unroll
        for (int a = 0; a < 3; ++a) {
            out[            (b*3 + a) * NPOINT + p] = xyz[(b*3 + a) * NPTS + fi];
            out[12288 +     (b*3 + a) * NPOINT + p] = nrm[(b*3 + a) * NPTS + n0];
            out[24576 +     (b*3 + a) * NPOINT + p] = Xa [(b*3 + a) * NPTS + n0];
            out[36864 +     (b*3 + a) * NPOINT + p] = Ya [(b*3 + a) * NPTS + n0];
        }
        return;
    }
    __shared__ float w1s[3][16][10];
    __shared__ float b1s[3][16];
    __shared__ float w2s[3][8][16];
    __shared__ float b2s[3][8];
    {
        const float* w1p[3] = {w1_0, w1_1, w1_2};
        const float* b1p[3] = {b1_0, b1_1, b1_2};
        const float* w2p[3] = {w2_0, w2_1, w2_2};
        const float* b2p[3] = {b2_0, b2_1, b2_2};
        #pragma unroll
        for (int l = 0; l < 3; ++l) {
            if (t < 160) w1s[l][t / 10][t % 10] = w1p[l][t];
            if (t < 16)  b1s[l][t] = b1p[l][t];
            if (t < 128) w2s[l][t / 16][t % 16] = w2p[l][t];
            if (t < 8)   b2s[l][t] = b2p[l][t];
        }
    }
    __syncthreads();
    const int row = bid * 256 + t;
    const int b = row >> 13;
    const int p = (row >> 4) & 511;
    const int n = g_knn[row] & (NPTS - 1);
    const int fi = g_fidx[b * NPOINT + p] & (NPTS - 1);
    const float* xb = xyz + b * 3 * NPTS;
    const float* nb = nrm + b * 3 * NPTS;
    const float* Xb = Xa  + b * 3 * NPTS;
    const float* Yb = Ya  + b * 3 * NPTS;
    float gx, gy, gz, sq, draw, nnv;
    {
        #pragma clang fp contract(off)
        gx = xb[n]        - xb[fi];
        gy = xb[NPTS + n] - xb[NPTS + fi];
        gz = xb[2*NPTS+n] - xb[2*NPTS+fi];
        sq = gx*gx + gy*gy;
        sq = sq + gz*gz;
        draw = sqrtf(sq + 1e-10f);
        nnv = sqrtf(sq);
    }
    float dmin = draw, dmax = draw;
    #pragma unroll
    for (int m = 1; m < 16; m <<= 1) {
        dmin = fminf(dmin, __shfl_xor(dmin, m, 16));
        dmax = fmaxf(dmax, __shfl_xor(dmax, m, 16));
    }
    float dist;
    {
        #pragma clang fp contract(off)
        dist = (draw - dmin) / ((dmax - dmin) + 1e-10f);
    }
    float nx = nb[n], ny = nb[NPTS+n], nz = nb[2*NPTS+n];
    float Xx = Xb[n], Xy = Xb[NPTS+n], Xz = Xb[2*NPTS+n];
    float Yx = Yb[n], Yy = Yb[NPTS+n], Yz = Yb[2*NPTS+n];
    float g[10];
    g[0]=gx; g[1]=gy; g[2]=gz; g[3]=dist; g[4]=nx; g[5]=ny; g[6]=nz;
    {
        float vs[3][3] = {{nx,ny,nz},{Xx,Xy,Xz},{Yx,Yy,Yz}};
        #pragma unroll
        for (int a = 0; a < 3; ++a) {
            float vx=vs[a][0], vy=vs[a][1], vz=vs[a][2];
            float dot, nv;
            {
                #pragma clang fp contract(off)
                dot = gx*vx + gy*vy; dot = dot + gz*vz;
                float s2 = vx*vx + vy*vy; s2 = s2 + vz*vz;
                nv = sqrtf(s2);
            }
            float cc = dot / (nnv * nv + 1e-8f);
            cc = fminf(1.0f, fmaxf(-1.0f, cc));
            g[7+a] = acosf(cc) / 3.14159274101257324f;
        }
    }
    #pragma unroll
    for (int l = 0; l < 3; ++l) {
        float h[16];
        #pragma unroll
        for (int i = 0; i < 16; ++i) {
            float a = b1s[l][i];
            #pragma unroll
            for (int j = 0; j < 10; ++j) a += w1s[l][i][j] * g[j];
            h[i] = fmaxf(a, 0.0f);
        }
        float e[8]; float mx = -1e30f;
        #pragma unroll
        for (int m = 0; m < 8; ++m) {
            float a = b2s[l][m];
            #pragma unroll
            for (int j = 0; j < 16; ++j) a += w2s[l][m][j] * h[j];
            e[m] = a; mx = fmaxf(mx, a);
        }
        float sum = 0.0f;
        #pragma unroll
        for (int m = 0; m < 8; ++m) { e[m] = expf(e[m] - mx); sum += e[m]; }
        #pragma unroll
        for (int m = 0; m < 8; ++m)
            g_S[(size_t)l * NROWS * 8 + (size_t)row * 8 + m] = e[m] / sum;
    }
}

// ---------------------------------------------------------------------------
// MFMA PAConv GEMM v6 (= r12 + LDS-only K-loop barrier):
//  - B fragments: one coalesced 16B/lane load from fragment-major g_bankF.
//  - As double-buffered on K-step parity; the K-loop barrier waits ONLY
//    lgkmcnt (LDS) -> B global loads pipeline across K-steps (no vmcnt drain).
//  - c0 outer / m inner: A row loaded+BN'd once per c-chunk (regs).
//  - LAYER>=1 staging applies previous BN+relu; LAYER<2 epilogue accumulates
//    per-channel sum/sumsq into g_sums (full __syncthreads there).
// ---------------------------------------------------------------------------
template<int LAYER, int CIN, int COUT>
__global__ __launch_bounds__(256) void gemm_kernel(const float* __restrict__ gamma,
                                                   const float* __restrict__ beta,
                                                   float* __restrict__ dout) {
    const float* __restrict__ A = (LAYER == 0) ? g_pT : (LAYER == 1) ? g_act1 : g_act2;
    float* __restrict__ O = (LAYER == 0) ? g_act1 : (LAYER == 1) ? g_act2 : dout;
    constexpr int NT = COUT / 16;
    constexpr int BOFF = (LAYER == 0) ? B0_OFF : (LAYER == 1) ? B1_OFF : B2_OFF;
    __shared__ ushort_t As[2][64][36];
    __shared__ float s_scale[(LAYER >= 1) ? CIN : 1];
    __shared__ float s_shift[(LAYER >= 1) ? CIN : 1];
    __shared__ float s_red[(LAYER < 2) ? 2 : 1][(LAYER < 2) ? 4 : 1][(LAYER < 2) ? COUT : 1];

    const int t = threadIdx.x;
    const int lane = t & 63, w = t >> 6;
    const int q = lane >> 4, nlo = lane & 15;
    const int row0 = blockIdx.x * 64;
    const int arow_i = t >> 2, acg = t & 3;

    if constexpr (LAYER >= 1) {
        const float* sb = (LAYER == 1) ? g_sums : (g_sums + 256);
        if (t < CIN) {
            float mu  = sb[t] * (1.0f / 65536.0f);
            float var = sb[CIN + t] * (1.0f / 65536.0f) - mu * mu;
            var = fmaxf(var, 0.0f);
            float sc = gamma[t] / sqrtf(var + 1e-5f);
            s_scale[t] = sc;
            s_shift[t] = beta[t] - mu * sc;
        }
        __syncthreads();
    }

    size_t arow;
    if (LAYER == 0) {
        const int row = row0 + arow_i;
        const int b = row >> 13;
        const int n = g_knn[row] & (NPTS - 1);
        arow = (size_t)(b * NPTS + n) * 64;
    } else {
        arow = (size_t)(row0 + arow_i) * CIN;
    }
    const float* Sbase = g_S + (size_t)LAYER * NROWS * 8 + (size_t)(row0 + arow_i) * 8;

    float svv[8];
    #pragma unroll
    for (int m = 0; m < 8; ++m) svv[m] = Sbase[m];

    f32x4 acc[NT];
    #pragma unroll
    for (int i = 0; i < NT; ++i) acc[i] = (f32x4){0.f, 0.f, 0.f, 0.f};

    // fragment base for this lane: chunk kc, tile nt -> + (kc*NT + nt)*512
    const ushort_t* fbase = g_bankF + BOFF + lane * 8;

    int par = 0;
    for (int c0 = 0; c0 < CIN; c0 += 32) {
        // ---- load F chunk once, BN+relu once ----
        float v[8];
        {
            const float* ap = A + arow + c0 + acg * 8;
            float4 fa = *reinterpret_cast<const float4*>(ap);
            float4 fb = *reinterpret_cast<const float4*>(ap + 4);
            v[0]=fa.x; v[1]=fa.y; v[2]=fa.z; v[3]=fa.w;
            v[4]=fb.x; v[5]=fb.y; v[6]=fb.z; v[7]=fb.w;
            if constexpr (LAYER >= 1) {
                const int c = c0 + acg * 8;
                #pragma unroll
                for (int j = 0; j < 8; ++j)
                    v[j] = fmaxf(v[j] * s_scale[c + j] + s_shift[c + j], 0.f);
            }
        }
        #pragma unroll
        for (int m = 0; m < 8; ++m) {
            // ---- stage A (sv[m]*F -> bf16) into parity buffer ----
            {
                const float sv = svv[m];
                uint_t* dst = reinterpret_cast<uint_t*>(&As[par][arow_i][acg * 8]);
                #pragma unroll
                for (int j = 0; j < 8; j += 2)
                    dst[j >> 1] = (uint_t)f2bf(sv * v[j]) | ((uint_t)f2bf(sv * v[j+1]) << 16);
            }
            LDS_BARRIER();   // LDS-only: B loads stay in flight across steps
            // ---- MFMA: A from LDS, B coalesced from g_bankF ----
            union FragU { uint2 u2[2]; short8 s; } af;
            af.u2[0] = *reinterpret_cast<const uint2*>(&As[par][w*16 + nlo][q*8]);
            af.u2[1] = *reinterpret_cast<const uint2*>(&As[par][w*16 + nlo][q*8 + 4]);
            const int kc = m * (CIN / 32) + (c0 >> 5);
            const ushort_t* bk = fbase + (size_t)(kc * NT) * 512;
            #pragma unroll
            for (int nt = 0; nt < NT; ++nt) {
                FragU bf;
                bf.u2[0] = *reinterpret_cast<const uint2*>(bk + (size_t)nt * 512);
                bf.u2[1] = *reinterpret_cast<const uint2*>(bk + (size_t)nt * 512 + 4);
                acc[nt] = __builtin_amdgcn_mfma_f32_16x16x32_bf16(af.s, bf.s, acc[nt], 0, 0, 0);
            }
            par ^= 1;
        }
    }

    if constexpr (LAYER == 2) {
        // wave w holds rows w*16..w*16+15 = all K=16 neighbors of one (b,p)
        const int bp = (row0 >> 4) + w;
        const int b = bp >> 9, p = bp & 511;
        #pragma unroll
        for (int nt = 0; nt < NT; ++nt) {
            float mv = fmaxf(fmaxf(acc[nt][0], acc[nt][1]), fmaxf(acc[nt][2], acc[nt][3]));
            mv = fmaxf(mv, __shfl_xor(mv, 16));
            mv = fmaxf(mv, __shfl_xor(mv, 32));
            if (lane < 16)
                O[(size_t)(b * 256 + nt*16 + nlo) * NPOINT + p] = mv;
        }
    } else {
        // raw output + fused per-channel sum/sumsq
        #pragma unroll
        for (int nt = 0; nt < NT; ++nt)
            #pragma unroll
            for (int r2 = 0; r2 < 4; ++r2)
                O[(size_t)(row0 + w*16 + q*4 + r2) * COUT + nt*16 + nlo] = acc[nt][r2];
        #pragma unroll
        for (int nt = 0; nt < NT; ++nt) {
            float s  = acc[nt][0] + acc[nt][1] + acc[nt][2] + acc[nt][3];
            float ss = acc[nt][0]*acc[nt][0] + acc[nt][1]*acc[nt][1]
                     + acc[nt][2]*acc[nt][2] + acc[nt][3]*acc[nt][3];
            s  += __shfl_xor(s, 16);  s  += __shfl_xor(s, 32);
            ss += __shfl_xor(ss, 16); ss += __shfl_xor(ss, 32);
            if (q == 0) {
                s_red[0][w][nt*16 + nlo] = s;
                s_red[1][w][nt*16 + nlo] = ss;
            }
        }
        __syncthreads();
        if (t < COUT) {
            float s  = s_red[0][0][t] + s_red[0][1][t] + s_red[0][2][t] + s_red[0][3][t];
            float ss = s_red[1][0][t] + s_red[1][1][t] + s_red[1][2][t] + s_red[1][3][t];
            float* sb = (LAYER == 0) ? g_sums : (g_sums + 256);
            atomicAdd(&sb[t], s);
            atomicAdd(&sb[COUT + t], ss);
        }
    }
}

// ---------------------------------------------------------------------------
extern "C" void kernel_launch(void* const* d_in, const int* in_sizes, int n_in,
                              void* d_out, int out_size, void* d_ws, size_t ws_size,
                              hipStream_t stream) {
    const float* xyz    = (const float*)d_in[0];
    const float* nrm    = (const float*)d_in[1];
    const float* Xa     = (const float*)d_in[2];
    const float* Ya     = (const float*)d_in[3];
    const float* points = (const float*)d_in[4];
    const float* w1_0 = (const float*)d_in[5];  const float* b1_0 = (const float*)d_in[6];
    const float* w2_0 = (const float*)d_in[7];  const float* b2_0 = (const float*)d_in[8];
    const float* bank0 = (const float*)d_in[9];
    const float* g0 = (const float*)d_in[10];   const float* be0 = (const float*)d_in[11];
    const float* w1_1 = (const float*)d_in[12]; const float* b1_1 = (const float*)d_in[13];
    const float* w2_1 = (const float*)d_in[14]; const float* b2_1 = (const float*)d_in[15];
    const float* bank1 = (const float*)d_in[16];
    const float* g1 = (const float*)d_in[17];   const float* be1 = (const float*)d_in[18];
    const float* w1_2 = (const float*)d_in[19]; const float* b1_2 = (const float*)d_in[20];
    const float* w2_2 = (const float*)d_in[21]; const float* b2_2 = (const float*)d_in[22];
    const float* bank2 = (const float*)d_in[23];
    float* out = (float*)d_out;
    (void)d_ws; (void)ws_size; (void)in_sizes; (void)n_in; (void)out_size;

    // fps (0-7) + transpose (8-263) + zero sums (264) + bank frag conv (265-1672)
    front_kernel<<<1673, 256, 0, stream>>>(xyz, points, bank0, bank1, bank2);
    knn_kernel<<<1024, 256, 0, stream>>>(xyz);
    // geometry + all 3 score MLPs (0-255) + small outputs (256-271)
    score3_kernel<<<272, 256, 0, stream>>>(xyz, nrm, Xa, Ya,
                                           w1_0, b1_0, w2_0, b2_0,
                                           w1_1, b1_1, w2_1, b2_1,
                                           w1_2, b1_2, w2_2, b2_2, out);
    // layer 0: gather+GEMM -> raw act1 + BN stats
    gemm_kernel<0, 64, 64><<<1024, 256, 0, stream>>>(nullptr, nullptr, nullptr);
    // layer 1: BN0+relu fused in staging -> raw act2 + BN stats
    gemm_kernel<1, 64, 128><<<1024, 256, 0, stream>>>(g0, be0, nullptr);
    // layer 2: BN1+relu fused in staging -> fused max-k + transpose to d_out
    gemm_kernel<2, 128, 256><<<1024, 256, 0, stream>>>(g1, be1, out + 49152);
}

// Round 15
// 572.629 us; speedup vs baseline: 1.4260x; 1.0742x over previous
//
#include <hip/hip_runtime.h>
#include <math.h>

#define NBATCH 8
#define NPTS   2048
#define NPOINT 512
#define KNB    16
#define NROWS  (NBATCH*NPOINT*KNB)   // 65536

typedef unsigned short ushort_t;
typedef unsigned int   uint_t;
typedef unsigned long long ull_t;
typedef __attribute__((ext_vector_type(8))) short  short8;   // 8 bf16 (4 VGPRs)
typedef __attribute__((ext_vector_type(4))) float  f32x4;    // MFMA C/D

// g_bankF element offsets (bf16, MFMA-fragment-major: [kc][nt][lane][8])
#define B0_OFF 0        // COUT=64,  K=512  -> 32768 elems
#define B1_OFF 32768    // COUT=128, K=512  -> 65536
#define B2_OFF 98304    // COUT=256, K=1024 -> 262144
#define BT_TOT 360448

// LDS-only workgroup barrier: orders LDS ops across waves WITHOUT draining
// vmcnt, so global (B-fragment) loads stay in flight across K-steps.
#define LDS_BARRIER() asm volatile("s_waitcnt lgkmcnt(0)\n\ts_barrier" ::: "memory")

// ---------------------------------------------------------------------------
// Scratch in static __device__ globals. Referenced ONLY in device code.
// ---------------------------------------------------------------------------
__device__ __align__(16) int      g_fidx[NBATCH * NPOINT];        //  16 KB
__device__ __align__(16) int      g_knn [NROWS];                  // 256 KB
__device__ __align__(16) float    g_sums[1024];                   //   4 KB
__device__ __align__(16) float    g_pT  [NBATCH * NPTS * 64];     //   4 MB
__device__ __align__(16) float    g_S   [(size_t)3 * NROWS * 8];  //   6 MB
__device__ __align__(16) float    g_act1[(size_t)NROWS * 64];     //  16 MB
__device__ __align__(16) float    g_act2[(size_t)NROWS * 128];    //  32 MB
__device__ __align__(16) ushort_t g_bankF[BT_TOT];                // 704 KB bf16 fragments

// f32 -> bf16 round-to-nearest-even (finite inputs).
__device__ __forceinline__ ushort_t f2bf(float f) {
    uint_t u = __float_as_uint(f);
    return (ushort_t)((u + 0x7FFFu + ((u >> 16) & 1u)) >> 16);
}

// DPP-shifted copy of a u64 key (bound_ctrl=1: invalid lanes read 0, the
// identity for unsigned max of our keys).
template<int CTRL>
__device__ __forceinline__ ull_t dpp_u64(ull_t k) {
    int lo = (int)(uint_t)k;
    int hi = (int)(uint_t)(k >> 32);
    int slo = __builtin_amdgcn_update_dpp(0, lo, CTRL, 0xF, 0xF, true);
    int shi = __builtin_amdgcn_update_dpp(0, hi, CTRL, 0xF, 0xF, true);
    return ((ull_t)(uint_t)shi << 32) | (uint_t)slo;
}

__device__ __forceinline__ ull_t dpp_max_u64(ull_t key) {
    { ull_t s = dpp_u64<0x111>(key); if (s > key) key = s; }  // row_shr:1
    { ull_t s = dpp_u64<0x112>(key); if (s > key) key = s; }  // row_shr:2
    { ull_t s = dpp_u64<0x114>(key); if (s > key) key = s; }  // row_shr:4
    { ull_t s = dpp_u64<0x118>(key); if (s > key) key = s; }  // row_shr:8
    { ull_t s = dpp_u64<0x142>(key); if (s > key) key = s; }  // row_bcast:15
    { ull_t s = dpp_u64<0x143>(key); if (s > key) key = s; }  // row_bcast:31
    return key;   // wave max in lane 63
}

// Convert one bank element into fragment-major bf16 layout.
// e enumerates (kc, nt, lane, j); value = bank[k=kc*32+q*8+j][n=nt*16+nlo].
template<int COUT>
__device__ __forceinline__ void bank_frag(const float* __restrict__ bank,
                                          ushort_t* __restrict__ dst, int e) {
    const int j = e & 7;
    const int lane = (e >> 3) & 63;
    const int rem = e >> 9;
    constexpr int NTL = COUT / 16;
    const int nt = rem % NTL;
    const int kc = rem / NTL;
    const int q = lane >> 4, nlo = lane & 15;
    const int k = kc * 32 + q * 8 + j;
    const int n = nt * 16 + nlo;
    dst[e] = f2bf(bank[(size_t)k * COUT + n]);
}

// ---------------------------------------------------------------------------
// front_kernel (r14-verbatim): blocks 0-7 = FPS; 8-263 = transpose points;
// 264 = zero sums; 265-1672 = bank fragment conversion (hidden under FPS).
// ---------------------------------------------------------------------------
__global__ __launch_bounds__(256) void front_kernel(const float* __restrict__ xyz,
                                                    const float* __restrict__ points,
                                                    const float* __restrict__ bank0,
                                                    const float* __restrict__ bank1,
                                                    const float* __restrict__ bank2) {
    __shared__ float smem[3 * NPTS + 16];
    const int bid = blockIdx.x;
    const int t = threadIdx.x;

    if (bid >= NBATCH) {
        if (bid < NBATCH + 256) {
            // ---- transpose points ----
            float (*tile)[65] = reinterpret_cast<float(*)[65]>(smem);
            const int blk = bid - NBATCH;
            const int b = blk >> 5;
            const int n0 = (blk & 31) * 64;
            const int lane = t & 63, q = t >> 6;
            #pragma unroll
            for (int i = 0; i < 16; ++i) {
                int c = q * 16 + i;
                tile[c][lane] = points[(b * 64 + c) * NPTS + n0 + lane];
            }
            __syncthreads();
            #pragma unroll
            for (int i = 0; i < 16; ++i) {
                int n = q * 16 + i;
                g_pT[(size_t)(b * NPTS + n0 + n) * 64 + lane] = tile[lane][n];
            }
        } else if (bid == NBATCH + 256) {
            // ---- zero BN-stats ----
            #pragma unroll
            for (int j = 0; j < 4; ++j) g_sums[j * 256 + t] = 0.0f;
        } else {
            // ---- bank -> fragment-major bf16 ----
            const int e = (bid - (NBATCH + 257)) * 256 + t;
            if (e < 32768) {
                bank_frag<64>(bank0, g_bankF + B0_OFF, e);
            } else if (e < 98304) {
                bank_frag<128>(bank1, g_bankF + B1_OFF, e - 32768);
            } else {
                bank_frag<256>(bank2, g_bankF + B2_OFF, e - 98304);
            }
        }
        return;
    }

    // ---- FPS ----
    {
        #pragma clang fp contract(off)
        const int b = bid;
        const int lane = t & 63, w4 = t >> 6;
        const float* xb = xyz + b * 3 * NPTS;
        float* s_x = smem;
        float* s_y = smem + NPTS;
        float* s_z = smem + 2 * NPTS;
        ull_t* s_key = reinterpret_cast<ull_t*>(smem + 3 * NPTS);  // 8 slots
        float x[8], y[8], z[8], d[8];
        #pragma unroll
        for (int j = 0; j < 8; ++j) {
            int p = j * 256 + t;
            float vx = xb[p], vy = xb[NPTS + p], vz = xb[2*NPTS + p];
            x[j] = vx; y[j] = vy; z[j] = vz;
            s_x[p] = vx; s_y[p] = vy; s_z[p] = vz;
            d[j] = 1e10f;
        }
        __syncthreads();
        int far = 0;
        for (int i = 0; i < NPOINT; ++i) {
            if (t == 0) g_fidx[b * NPOINT + i] = far;
            float cx = s_x[far], cy = s_y[far], cz = s_z[far];
            float best = -1.0f; int bi = 0;
            #pragma unroll
            for (int j = 0; j < 8; ++j) {
                float dx = x[j] - cx;
                float dy = y[j] - cy;
                float dz = z[j] - cz;
                float dd = dx*dx + dy*dy;   // ((dx^2+dy^2)+dz^2) like np
                dd = dd + dz*dz;
                float dn = fminf(d[j], dd);
                d[j] = dn;
                if (dn > best) { best = dn; bi = j * 256 + t; }  // strict >
            }
            ull_t key = (((ull_t)__float_as_uint(best)) << 32) | (uint_t)(~bi);
            key = dpp_max_u64(key);
            uint_t wlo = (uint_t)__builtin_amdgcn_readlane((int)(uint_t)key, 63);
            uint_t whi = (uint_t)__builtin_amdgcn_readlane((int)(uint_t)(key >> 32), 63);
            if (lane == 0) s_key[((i & 1) << 2) + w4] = ((ull_t)whi << 32) | wlo;
            __syncthreads();
            const ull_t* kb = s_key + ((i & 1) << 2);
            ull_t k0 = kb[0], k1 = kb[1], k2 = kb[2], k3 = kb[3];
            if (k1 > k0) k0 = k1;
            if (k3 > k2) k2 = k3;
            if (k2 > k0) k0 = k2;
            far = (int)(~(uint_t)k0) & (NPTS - 1);
        }
    }
}

// ---------------------------------------------------------------------------
// knn_score_kernel: one wave per query (b,p). KNN (r14 DPP argmin), with
// lane k (k<16) keeping neighbor k's index in-register; then lanes 0-15
// compute geometry + all THREE scoring MLPs for their row (b,p,k) directly
// (dist min/max over k = width-16 shuffles within lanes 0-15).
// ---------------------------------------------------------------------------
__global__ __launch_bounds__(256) void knn_score_kernel(
    const float* __restrict__ xyz, const float* __restrict__ nrm,
    const float* __restrict__ Xa, const float* __restrict__ Ya,
    const float* __restrict__ w1_0, const float* __restrict__ b1_0,
    const float* __restrict__ w2_0, const float* __restrict__ b2_0,
    const float* __restrict__ w1_1, const float* __restrict__ b1_1,
    const float* __restrict__ w2_1, const float* __restrict__ b2_1,
    const float* __restrict__ w1_2, const float* __restrict__ b1_2,
    const float* __restrict__ w2_2, const float* __restrict__ b2_2) {
    __shared__ float w1s[3][16][10];
    __shared__ float b1s[3][16];
    __shared__ float w2s[3][8][16];
    __shared__ float b2s[3][8];
    const int t = threadIdx.x;
    {
        const float* w1p[3] = {w1_0, w1_1, w1_2};
        const float* b1p[3] = {b1_0, b1_1, b1_2};
        const float* w2p[3] = {w2_0, w2_1, w2_2};
        const float* b2p[3] = {b2_0, b2_1, b2_2};
        #pragma unroll
        for (int l = 0; l < 3; ++l) {
            if (t < 160) w1s[l][t / 10][t % 10] = w1p[l][t];
            if (t < 16)  b1s[l][t] = b1p[l][t];
            if (t < 128) w2s[l][t / 16][t % 16] = w2p[l][t];
            if (t < 8)   b2s[l][t] = b2p[l][t];
        }
    }
    __syncthreads();

    const int wave = blockIdx.x * 4 + (t >> 6);   // = b*512 + p
    const int lane = t & 63;
    const int b = wave >> 9;
    const int p = wave & 511;
    const float* xb = xyz + b * 3 * NPTS;
    const int fi = g_fidx[wave] & (NPTS - 1);
    int nmine = 0;   // lane k<16: index of neighbor k after the loop

    {
        #pragma clang fp contract(off)
        float ax = xb[fi];
        float ay = xb[NPTS + fi];
        float az = xb[2*NPTS + fi];
        float sa = ax*ax + ay*ay; sa = sa + az*az;
        float d[32];
        #pragma unroll
        for (int j = 0; j < 32; ++j) {
            int pp = j * 64 + lane;
            float bx = xb[pp];
            float by = xb[NPTS + pp];
            float bz = xb[2*NPTS + pp];
            float sb = bx*bx + by*by; sb = sb + bz*bz;
            float dot = ax*bx + ay*by; dot = dot + az*bz;
            float t1 = sa + sb;
            float t2 = 2.0f * dot;
            d[j] = t1 - t2;
        }
        for (int r = 0; r < KNB; ++r) {
            float best = 1e30f; int bi = 0x7fffffff;
            #pragma unroll
            for (int j = 0; j < 32; ++j) {
                if (d[j] < best) { best = d[j]; bi = j * 64 + lane; }
            }
            uint_t ub = __float_as_uint(best);
            ub = (ub & 0x80000000u) ? ~ub : (ub | 0x80000000u);   // ascending map
            ull_t key = ((ull_t)(~ub) << 32) | (uint_t)(~bi);
            key = dpp_max_u64(key);
            uint_t wlo = (uint_t)__builtin_amdgcn_readlane((int)(uint_t)key, 63);
            bi = (int)(~wlo) & (NPTS - 1);
            if (lane == 0) g_knn[wave * KNB + r] = bi;
            if (lane == r) nmine = bi;
            int rl = bi & 63, rs = bi >> 6;
            if (lane == rl) {
                #pragma unroll
                for (int j = 0; j < 32; ++j) if (j == rs) d[j] = 1e30f;
            }
        }
    }

    // ---- score phase: lanes 0-15 each handle row (b,p,k=lane) ----
    if (lane < 16) {
        const int row = wave * KNB + lane;
        const int n = nmine & (NPTS - 1);
        const float* nb = nrm + b * 3 * NPTS;
        const float* Xb = Xa  + b * 3 * NPTS;
        const float* Yb = Ya  + b * 3 * NPTS;
        float gx, gy, gz, sq, draw, nnv;
        {
            #pragma clang fp contract(off)
            gx = xb[n]        - xb[fi];
            gy = xb[NPTS + n] - xb[NPTS + fi];
            gz = xb[2*NPTS+n] - xb[2*NPTS+fi];
            sq = gx*gx + gy*gy;
            sq = sq + gz*gz;
            draw = sqrtf(sq + 1e-10f);
            nnv = sqrtf(sq);
        }
        float dmin = draw, dmax = draw;
        #pragma unroll
        for (int m = 1; m < 16; m <<= 1) {
            dmin = fminf(dmin, __shfl_xor(dmin, m, 16));
            dmax = fmaxf(dmax, __shfl_xor(dmax, m, 16));
        }
        float dist;
        {
            #pragma clang fp contract(off)
            dist = (draw - dmin) / ((dmax - dmin) + 1e-10f);
        }
        float nx = nb[n], ny = nb[NPTS+n], nz = nb[2*NPTS+n];
        float Xx = Xb[n], Xy = Xb[NPTS+n], Xz = Xb[2*NPTS+n];
        float Yx = Yb[n], Yy = Yb[NPTS+n], Yz = Yb[2*NPTS+n];
        float g[10];
        g[0]=gx; g[1]=gy; g[2]=gz; g[3]=dist; g[4]=nx; g[5]=ny; g[6]=nz;
        {
            float vs[3][3] = {{nx,ny,nz},{Xx,Xy,Xz},{Yx,Yy,Yz}};
            #pragma unroll
            for (int a = 0; a < 3; ++a) {
                float vx=vs[a][0], vy=vs[a][1], vz=vs[a][2];
                float dot, nv;
                {
                    #pragma clang fp contract(off)
                    dot = gx*vx + gy*vy; dot = dot + gz*vz;
                    float s2 = vx*vx + vy*vy; s2 = s2 + vz*vz;
                    nv = sqrtf(s2);
                }
                float cc = dot / (nnv * nv + 1e-8f);
                cc = fminf(1.0f, fmaxf(-1.0f, cc));
                g[7+a] = acosf(cc) / 3.14159274101257324f;
            }
        }
        #pragma unroll
        for (int l = 0; l < 3; ++l) {
            float h[16];
            #pragma unroll
            for (int i = 0; i < 16; ++i) {
                float a = b1s[l][i];
                #pragma unroll
                for (int j = 0; j < 10; ++j) a += w1s[l][i][j] * g[j];
                h[i] = fmaxf(a, 0.0f);
            }
            float e[8]; float mx = -1e30f;
            #pragma unroll
            for (int m = 0; m < 8; ++m) {
                float a = b2s[l][m];
                #pragma unroll
                for (int j = 0; j < 16; ++j) a += w2s[l][m][j] * h[j];
                e[m] = a; mx = fmaxf(mx, a);
            }
            float sum = 0.0f;
            #pragma unroll
            for (int m = 0; m < 8; ++m) { e[m] = expf(e[m] - mx); sum += e[m]; }
            #pragma unroll
            for (int m = 0; m < 8; ++m)
                g_S[(size_t)l * NROWS * 8 + (size_t)row * 8 + m] = e[m] / sum;
        }
    }
}

// ---------------------------------------------------------------------------
// MFMA PAConv GEMM v7 — wave retiling for B reuse:
// block = 64 rows x full COUT; wave w computes ALL 64 rows x a 64-col slice
// (4 A-frags from the shared LDS A-tile x NTW=COUT/64 B-frags). B traffic
// per wave /4 vs v6; MFMA per barrier x4. A staged cooperatively (parity
// double-buffer, LDS-only barrier). B frags: coalesced 16B/lane from g_bankF.
// LAYER 0 also hosts small_out on blocks >= 1024.
// ---------------------------------------------------------------------------
template<int LAYER, int CIN, int COUT>
__global__ __launch_bounds__(256) void gemm_kernel(const float* __restrict__ gamma,
                                                   const float* __restrict__ beta,
                                                   float* __restrict__ dout,
                                                   const float* __restrict__ xyz,
                                                   const float* __restrict__ nrm,
                                                   const float* __restrict__ Xa,
                                                   const float* __restrict__ Ya) {
    if constexpr (LAYER == 0) {
        if (blockIdx.x >= 1024) {
            // ---- small outputs: new_xyz (fidx), new_norm/X/Y (knn[...,0]) ----
            const int g = (blockIdx.x - 1024) * 256 + threadIdx.x;   // b*512+p
            const int b = g / NPOINT, p = g % NPOINT;
            const int fi = g_fidx[g] & (NPTS - 1);
            const int n0 = g_knn[g * KNB] & (NPTS - 1);
            #pragma unroll
            for (int a = 0; a < 3; ++a) {
                dout[            (b*3 + a) * NPOINT + p] = xyz[(b*3 + a) * NPTS + fi];
                dout[12288 +     (b*3 + a) * NPOINT + p] = nrm[(b*3 + a) * NPTS + n0];
                dout[24576 +     (b*3 + a) * NPOINT + p] = Xa [(b*3 + a) * NPTS + n0];
                dout[36864 +     (b*3 + a) * NPOINT + p] = Ya [(b*3 + a) * NPTS + n0];
            }
            return;
        }
    }

    const float* __restrict__ A = (LAYER == 0) ? g_pT : (LAYER == 1) ? g_act1 : g_act2;
    float* __restrict__ O = (LAYER == 0) ? g_act1 : (LAYER == 1) ? g_act2 : dout;
    constexpr int NTT = COUT / 16;    // total col tiles
    constexpr int NTW = NTT / 4;      // col tiles per wave (g0:1 g1:2 g2:4)
    constexpr int BOFF = (LAYER == 0) ? B0_OFF : (LAYER == 1) ? B1_OFF : B2_OFF;
    __shared__ ushort_t As[2][64][36];
    __shared__ float s_scale[(LAYER >= 1) ? CIN : 1];
    __shared__ float s_shift[(LAYER >= 1) ? CIN : 1];
    __shared__ float s_rs[(LAYER < 2) ? COUT : 1];
    __shared__ float s_rss[(LAYER < 2) ? COUT : 1];

    const int t = threadIdx.x;
    const int lane = t & 63, w = t >> 6;
    const int q = lane >> 4, nlo = lane & 15;
    const int row0 = blockIdx.x * 64;
    const int arow_i = t >> 2, acg = t & 3;

    if constexpr (LAYER >= 1) {
        const float* sb = (LAYER == 1) ? g_sums : (g_sums + 256);
        if (t < CIN) {
            float mu  = sb[t] * (1.0f / 65536.0f);
            float var = sb[CIN + t] * (1.0f / 65536.0f) - mu * mu;
            var = fmaxf(var, 0.0f);
            float sc = gamma[t] / sqrtf(var + 1e-5f);
            s_scale[t] = sc;
            s_shift[t] = beta[t] - mu * sc;
        }
        __syncthreads();
    }

    size_t arow;
    if (LAYER == 0) {
        const int row = row0 + arow_i;
        const int b = row >> 13;
        const int n = g_knn[row] & (NPTS - 1);
        arow = (size_t)(b * NPTS + n) * 64;
    } else {
        arow = (size_t)(row0 + arow_i) * CIN;
    }
    const float* Sbase = g_S + (size_t)LAYER * NROWS * 8 + (size_t)(row0 + arow_i) * 8;

    float svv[8];
    #pragma unroll
    for (int m = 0; m < 8; ++m) svv[m] = Sbase[m];

    f32x4 acc[4][NTW];
    #pragma unroll
    for (int mi = 0; mi < 4; ++mi)
        #pragma unroll
        for (int ni = 0; ni < NTW; ++ni) acc[mi][ni] = (f32x4){0.f, 0.f, 0.f, 0.f};

    const ushort_t* fbase = g_bankF + BOFF + lane * 8;

    union FragU { uint2 u2[2]; short8 s; };
    int par = 0;
    for (int c0 = 0; c0 < CIN; c0 += 32) {
        // ---- load F chunk once, BN+relu once ----
        float v[8];
        {
            const float* ap = A + arow + c0 + acg * 8;
            float4 fa = *reinterpret_cast<const float4*>(ap);
            float4 fb = *reinterpret_cast<const float4*>(ap + 4);
            v[0]=fa.x; v[1]=fa.y; v[2]=fa.z; v[3]=fa.w;
            v[4]=fb.x; v[5]=fb.y; v[6]=fb.z; v[7]=fb.w;
            if constexpr (LAYER >= 1) {
                const int c = c0 + acg * 8;
                #pragma unroll
                for (int j = 0; j < 8; ++j)
                    v[j] = fmaxf(v[j] * s_scale[c + j] + s_shift[c + j], 0.f);
            }
        }
        #pragma unroll
        for (int m = 0; m < 8; ++m) {
            // ---- stage A (sv[m]*F -> bf16) into parity buffer ----
            {
                const float sv = svv[m];
                uint_t* dst = reinterpret_cast<uint_t*>(&As[par][arow_i][acg * 8]);
                #pragma unroll
                for (int j = 0; j < 8; j += 2)
                    dst[j >> 1] = (uint_t)f2bf(sv * v[j]) | ((uint_t)f2bf(sv * v[j+1]) << 16);
            }
            LDS_BARRIER();   // LDS-only: B loads stay in flight across steps
            // ---- A fragments: all 4 row-tiles of the block ----
            FragU af[4];
            #pragma unroll
            for (int mi = 0; mi < 4; ++mi) {
                af[mi].u2[0] = *reinterpret_cast<const uint2*>(&As[par][mi*16 + nlo][q*8]);
                af[mi].u2[1] = *reinterpret_cast<const uint2*>(&As[par][mi*16 + nlo][q*8 + 4]);
            }
            // ---- B fragments (this wave's col slice) + MFMAs ----
            const int kc = m * (CIN / 32) + (c0 >> 5);
            #pragma unroll
            for (int ni = 0; ni < NTW; ++ni) {
                const ushort_t* bk = fbase + (size_t)(kc * NTT + w * NTW + ni) * 512;
                FragU bf;
                bf.u2[0] = *reinterpret_cast<const uint2*>(bk);
                bf.u2[1] = *reinterpret_cast<const uint2*>(bk + 4);
                #pragma unroll
                for (int mi = 0; mi < 4; ++mi)
                    acc[mi][ni] = __builtin_amdgcn_mfma_f32_16x16x32_bf16(af[mi].s, bf.s, acc[mi][ni], 0, 0, 0);
            }
            par ^= 1;
        }
    }

    if constexpr (LAYER == 2) {
        // row-tile mi = bp group row0/16 + mi; cols w*64 + ni*16 + nlo
        const int bp0 = row0 >> 4;
        #pragma unroll
        for (int mi = 0; mi < 4; ++mi) {
            const int bp = bp0 + mi;
            const int b = bp >> 9, p = bp & 511;
            #pragma unroll
            for (int ni = 0; ni < NTW; ++ni) {
                float mv = fmaxf(fmaxf(acc[mi][ni][0], acc[mi][ni][1]),
                                 fmaxf(acc[mi][ni][2], acc[mi][ni][3]));
                mv = fmaxf(mv, __shfl_xor(mv, 16));
                mv = fmaxf(mv, __shfl_xor(mv, 32));
                if (lane < 16) {
                    const int col = w * 64 + ni * 16 + nlo;
                    O[(size_t)(b * 256 + col) * NPOINT + p] = mv;
                }
            }
        }
    } else {
        // raw output + fused per-channel sum/sumsq
        #pragma unroll
        for (int mi = 0; mi < 4; ++mi)
            #pragma unroll
            for (int ni = 0; ni < NTW; ++ni)
                #pragma unroll
                for (int r2 = 0; r2 < 4; ++r2)
                    O[(size_t)(row0 + mi*16 + q*4 + r2) * COUT + w*NTW*16 + ni*16 + nlo] = acc[mi][ni][r2];
        #pragma unroll
        for (int ni = 0; ni < NTW; ++ni) {
            float s = 0.f, ss = 0.f;
            #pragma unroll
            for (int mi = 0; mi < 4; ++mi) {
                #pragma unroll
                for (int r2 = 0; r2 < 4; ++r2) {
                    float x = acc[mi][ni][r2];
                    s += x; ss += x * x;
                }
            }
            s  += __shfl_xor(s, 16);  s  += __shfl_xor(s, 32);
            ss += __shfl_xor(ss, 16); ss += __shfl_xor(ss, 32);
            if (q == 0) {
                const int c = w * NTW * 16 + ni * 16 + nlo;   // unique owner
                s_rs[c] = s;
                s_rss[c] = ss;
            }
        }
        __syncthreads();
        if (t < COUT) {
            float* sb = (LAYER == 0) ? g_sums : (g_sums + 256);
            atomicAdd(&sb[t], s_rs[t]);
            atomicAdd(&sb[COUT + t], s_rss[t]);
        }
    }
}

// ---------------------------------------------------------------------------
extern "C" void kernel_launch(void* const* d_in, const int* in_sizes, int n_in,
                              void* d_out, int out_size, void* d_ws, size_t ws_size,
                              hipStream_t stream) {
    const float* xyz    = (const float*)d_in[0];
    const float* nrm    = (const float*)d_in[1];
    const float* Xa     = (const float*)d_in[2];
    const float* Ya     = (const float*)d_in[3];
    const float* points = (const float*)d_in[4];
    const float* w1_0 = (const float*)d_in[5];  const float* b1_0 = (const float*)d_in[6];
    const float* w2_0 = (const float*)d_in[7];  const float* b2_0 = (const float*)d_in[8];
    const float* bank0 = (const float*)d_in[9];
    const float* g0 = (const float*)d_in[10];   const float* be0 = (const float*)d_in[11];
    const float* w1_1 = (const float*)d_in[12]; const float* b1_1 = (const float*)d_in[13];
    const float* w2_1 = (const float*)d_in[14]; const float* b2_1 = (const float*)d_in[15];
    const float* bank1 = (const float*)d_in[16];
    const float* g1 = (const float*)d_in[17];   const float* be1 = (const float*)d_in[18];
    const float* w1_2 = (const float*)d_in[19]; const float* b1_2 = (const float*)d_in[20];
    const float* w2_2 = (const float*)d_in[21]; const float* b2_2 = (const float*)d_in[22];
    const float* bank2 = (const float*)d_in[23];
    float* out = (float*)d_out;
    (void)d_ws; (void)ws_size; (void)in_sizes; (void)n_in; (void)out_size;

    // fps (0-7) + transpose (8-263) + zero sums (264) + bank frag conv (265-1672)
    front_kernel<<<1673, 256, 0, stream>>>(xyz, points, bank0, bank1, bank2);
    // KNN + geometry + all 3 score MLPs (fused per wave)
    knn_score_kernel<<<1024, 256, 0, stream>>>(xyz, nrm, Xa, Ya,
                                               w1_0, b1_0, w2_0, b2_0,
                                               w1_1, b1_1, w2_1, b2_1,
                                               w1_2, b1_2, w2_2, b2_2);
    // layer 0: gather+GEMM -> raw act1 + BN stats; blocks 1024+ = small_out
    gemm_kernel<0, 64, 64><<<1040, 256, 0, stream>>>(nullptr, nullptr, out, xyz, nrm, Xa, Ya);
    // layer 1: BN0+relu fused in staging -> raw act2 + BN stats
    gemm_kernel<1, 64, 128><<<1024, 256, 0, stream>>>(g0, be0, nullptr, nullptr, nullptr, nullptr, nullptr);
    // layer 2: BN1+relu fused in staging -> fused max-k + transpose to d_out
    gemm_kernel<2, 128, 256><<<1024, 256, 0, stream>>>(g1, be1, out + 49152, nullptr, nullptr, nullptr, nullptr);
}

// Round 16
// 507.597 us; speedup vs baseline: 1.6086x; 1.1281x over previous
//
#include <hip/hip_runtime.h>
#include <math.h>

#define NBATCH 8
#define NPTS   2048
#define NPOINT 512
#define KNB    16
#define NROWS  (NBATCH*NPOINT*KNB)   // 65536

typedef unsigned short ushort_t;
typedef unsigned int   uint_t;
typedef unsigned long long ull_t;
typedef __attribute__((ext_vector_type(8))) short  short8;   // 8 bf16 (4 VGPRs)
typedef __attribute__((ext_vector_type(4))) float  f32x4;    // MFMA C/D

// g_bankF element offsets (bf16, MFMA-fragment-major: [kc][nt][lane][8])
#define B0_OFF 0        // COUT=64,  K=512  -> 32768 elems
#define B1_OFF 32768    // COUT=128, K=512  -> 65536
#define B2_OFF 98304    // COUT=256, K=1024 -> 262144
#define BT_TOT 360448

// LDS-only workgroup barrier: orders LDS ops across waves WITHOUT draining
// vmcnt, so global (B-fragment) loads stay in flight across K-steps.
#define LDS_BARRIER() asm volatile("s_waitcnt lgkmcnt(0)\n\ts_barrier" ::: "memory")

// ---------------------------------------------------------------------------
// Scratch in static __device__ globals. Referenced ONLY in device code.
// ---------------------------------------------------------------------------
__device__ __align__(16) int      g_fidx[NBATCH * NPOINT];        //  16 KB
__device__ __align__(16) int      g_knn [NROWS];                  // 256 KB
__device__ __align__(16) float    g_sums[1024];                   //   4 KB
__device__ __align__(16) float    g_pT  [NBATCH * NPTS * 64];     //   4 MB
__device__ __align__(16) float    g_S   [(size_t)3 * NROWS * 8];  //   6 MB
__device__ __align__(16) float    g_act1[(size_t)NROWS * 64];     //  16 MB
__device__ __align__(16) float    g_act2[(size_t)NROWS * 128];    //  32 MB
__device__ __align__(16) ushort_t g_bankF[BT_TOT];                // 704 KB bf16 fragments

// f32 -> bf16 round-to-nearest-even (finite inputs).
__device__ __forceinline__ ushort_t f2bf(float f) {
    uint_t u = __float_as_uint(f);
    return (ushort_t)((u + 0x7FFFu + ((u >> 16) & 1u)) >> 16);
}

// DPP-shifted copy of a u64 key (bound_ctrl=1: invalid lanes read 0, the
// identity for unsigned max of our keys).
template<int CTRL>
__device__ __forceinline__ ull_t dpp_u64(ull_t k) {
    int lo = (int)(uint_t)k;
    int hi = (int)(uint_t)(k >> 32);
    int slo = __builtin_amdgcn_update_dpp(0, lo, CTRL, 0xF, 0xF, true);
    int shi = __builtin_amdgcn_update_dpp(0, hi, CTRL, 0xF, 0xF, true);
    return ((ull_t)(uint_t)shi << 32) | (uint_t)slo;
}

__device__ __forceinline__ ull_t dpp_max_u64(ull_t key) {
    { ull_t s = dpp_u64<0x111>(key); if (s > key) key = s; }  // row_shr:1
    { ull_t s = dpp_u64<0x112>(key); if (s > key) key = s; }  // row_shr:2
    { ull_t s = dpp_u64<0x114>(key); if (s > key) key = s; }  // row_shr:4
    { ull_t s = dpp_u64<0x118>(key); if (s > key) key = s; }  // row_shr:8
    { ull_t s = dpp_u64<0x142>(key); if (s > key) key = s; }  // row_bcast:15
    { ull_t s = dpp_u64<0x143>(key); if (s > key) key = s; }  // row_bcast:31
    return key;   // wave max in lane 63
}

// Convert one bank element into fragment-major bf16 layout.
// e enumerates (kc, nt, lane, j); value = bank[k=kc*32+q*8+j][n=nt*16+nlo].
template<int COUT>
__device__ __forceinline__ void bank_frag(const float* __restrict__ bank,
                                          ushort_t* __restrict__ dst, int e) {
    const int j = e & 7;
    const int lane = (e >> 3) & 63;
    const int rem = e >> 9;
    constexpr int NTL = COUT / 16;
    const int nt = rem % NTL;
    const int kc = rem / NTL;
    const int q = lane >> 4, nlo = lane & 15;
    const int k = kc * 32 + q * 8 + j;
    const int n = nt * 16 + nlo;
    dst[e] = f2bf(bank[(size_t)k * COUT + n]);
}

// ---------------------------------------------------------------------------
// front_kernel (512 threads): blocks 0-7 = FPS (8 waves, 4 pts/lane);
// 8-263 = transpose points; 264 = zero sums; 265-968 = bank fragment conv.
// FPS: DPP wave argmax -> lane 63, packed key (f32bits(dist)<<32)|~idx,
// parity-buffered 8-slot s_key, 1 barrier/iter. Identical selection
// semantics to r14 (verified); j-loop halved by the wider block.
// ---------------------------------------------------------------------------
__global__ __launch_bounds__(512) void front_kernel(const float* __restrict__ xyz,
                                                    const float* __restrict__ points,
                                                    const float* __restrict__ bank0,
                                                    const float* __restrict__ bank1,
                                                    const float* __restrict__ bank2) {
    __shared__ float smem[3 * NPTS];
    __shared__ ull_t s_key[2][8];
    const int bid = blockIdx.x;
    const int t = threadIdx.x;

    if (bid >= NBATCH) {
        if (bid < NBATCH + 256) {
            // ---- transpose points (one 64x64 tile, 8 elems/thread) ----
            float (*tile)[65] = reinterpret_cast<float(*)[65]>(smem);
            const int blk = bid - NBATCH;
            const int b = blk >> 5;
            const int n0 = (blk & 31) * 64;
            const int lane = t & 63, q = t >> 6;   // q in [0,8)
            #pragma unroll
            for (int i = 0; i < 8; ++i) {
                int c = q * 8 + i;
                tile[c][lane] = points[(b * 64 + c) * NPTS + n0 + lane];
            }
            __syncthreads();
            #pragma unroll
            for (int i = 0; i < 8; ++i) {
                int n = q * 8 + i;
                g_pT[(size_t)(b * NPTS + n0 + n) * 64 + lane] = tile[lane][n];
            }
        } else if (bid == NBATCH + 256) {
            // ---- zero BN-stats ----
            g_sums[t] = 0.0f;
            g_sums[512 + t] = 0.0f;
        } else {
            // ---- bank -> fragment-major bf16 ----
            const int e = (bid - (NBATCH + 257)) * 512 + t;
            if (e < 32768) {
                bank_frag<64>(bank0, g_bankF + B0_OFF, e);
            } else if (e < 98304) {
                bank_frag<128>(bank1, g_bankF + B1_OFF, e - 32768);
            } else {
                bank_frag<256>(bank2, g_bankF + B2_OFF, e - 98304);
            }
        }
        return;
    }

    // ---- FPS ----
    {
        #pragma clang fp contract(off)
        const int b = bid;
        const int lane = t & 63, w8 = t >> 6;   // 8 waves
        const float* xb = xyz + b * 3 * NPTS;
        float* s_x = smem;
        float* s_y = smem + NPTS;
        float* s_z = smem + 2 * NPTS;
        float x[4], y[4], z[4], d[4];
        #pragma unroll
        for (int j = 0; j < 4; ++j) {
            int p = j * 512 + t;
            float vx = xb[p], vy = xb[NPTS + p], vz = xb[2*NPTS + p];
            x[j] = vx; y[j] = vy; z[j] = vz;
            s_x[p] = vx; s_y[p] = vy; s_z[p] = vz;
            d[j] = 1e10f;
        }
        __syncthreads();
        int far = 0;
        for (int i = 0; i < NPOINT; ++i) {
            if (t == 0) g_fidx[b * NPOINT + i] = far;
            float cx = s_x[far], cy = s_y[far], cz = s_z[far];
            float best = -1.0f; int bi = 0;
            #pragma unroll
            for (int j = 0; j < 4; ++j) {
                float dx = x[j] - cx;
                float dy = y[j] - cy;
                float dz = z[j] - cz;
                float dd = dx*dx + dy*dy;   // ((dx^2+dy^2)+dz^2) like np
                dd = dd + dz*dz;
                float dn = fminf(d[j], dd);
                d[j] = dn;
                if (dn > best) { best = dn; bi = j * 512 + t; }  // strict >
            }
            ull_t key = (((ull_t)__float_as_uint(best)) << 32) | (uint_t)(~bi);
            key = dpp_max_u64(key);
            uint_t wlo = (uint_t)__builtin_amdgcn_readlane((int)(uint_t)key, 63);
            uint_t whi = (uint_t)__builtin_amdgcn_readlane((int)(uint_t)(key >> 32), 63);
            if (lane == 0) s_key[i & 1][w8] = ((ull_t)whi << 32) | wlo;
            __syncthreads();
            const ull_t* kb = s_key[i & 1];
            ull_t k0 = kb[0], k1 = kb[1], k2 = kb[2], k3 = kb[3];
            ull_t k4 = kb[4], k5 = kb[5], k6 = kb[6], k7 = kb[7];
            if (k1 > k0) k0 = k1;
            if (k3 > k2) k2 = k3;
            if (k5 > k4) k4 = k5;
            if (k7 > k6) k6 = k7;
            if (k2 > k0) k0 = k2;
            if (k6 > k4) k4 = k6;
            if (k4 > k0) k0 = k4;
            far = (int)(~(uint_t)k0) & (NPTS - 1);
        }
    }
}

// ---------------------------------------------------------------------------
// knn_score_kernel (r15-verbatim): one wave per query; KNN DPP argmin with
// lane k keeping neighbor k; lanes 0-15 then compute geometry + all 3 MLPs.
// ---------------------------------------------------------------------------
__global__ __launch_bounds__(256) void knn_score_kernel(
    const float* __restrict__ xyz, const float* __restrict__ nrm,
    const float* __restrict__ Xa, const float* __restrict__ Ya,
    const float* __restrict__ w1_0, const float* __restrict__ b1_0,
    const float* __restrict__ w2_0, const float* __restrict__ b2_0,
    const float* __restrict__ w1_1, const float* __restrict__ b1_1,
    const float* __restrict__ w2_1, const float* __restrict__ b2_1,
    const float* __restrict__ w1_2, const float* __restrict__ b1_2,
    const float* __restrict__ w2_2, const float* __restrict__ b2_2) {
    __shared__ float w1s[3][16][10];
    __shared__ float b1s[3][16];
    __shared__ float w2s[3][8][16];
    __shared__ float b2s[3][8];
    const int t = threadIdx.x;
    {
        const float* w1p[3] = {w1_0, w1_1, w1_2};
        const float* b1p[3] = {b1_0, b1_1, b1_2};
        const float* w2p[3] = {w2_0, w2_1, w2_2};
        const float* b2p[3] = {b2_0, b2_1, b2_2};
        #pragma unroll
        for (int l = 0; l < 3; ++l) {
            if (t < 160) w1s[l][t / 10][t % 10] = w1p[l][t];
            if (t < 16)  b1s[l][t] = b1p[l][t];
            if (t < 128) w2s[l][t / 16][t % 16] = w2p[l][t];
            if (t < 8)   b2s[l][t] = b2p[l][t];
        }
    }
    __syncthreads();

    const int wave = blockIdx.x * 4 + (t >> 6);   // = b*512 + p
    const int lane = t & 63;
    const int b = wave >> 9;
    const float* xb = xyz + b * 3 * NPTS;
    const int fi = g_fidx[wave] & (NPTS - 1);
    int nmine = 0;   // lane k<16: index of neighbor k after the loop

    {
        #pragma clang fp contract(off)
        float ax = xb[fi];
        float ay = xb[NPTS + fi];
        float az = xb[2*NPTS + fi];
        float sa = ax*ax + ay*ay; sa = sa + az*az;
        float d[32];
        #pragma unroll
        for (int j = 0; j < 32; ++j) {
            int pp = j * 64 + lane;
            float bx = xb[pp];
            float by = xb[NPTS + pp];
            float bz = xb[2*NPTS + pp];
            float sb = bx*bx + by*by; sb = sb + bz*bz;
            float dot = ax*bx + ay*by; dot = dot + az*bz;
            float t1 = sa + sb;
            float t2 = 2.0f * dot;
            d[j] = t1 - t2;
        }
        for (int r = 0; r < KNB; ++r) {
            float best = 1e30f; int bi = 0x7fffffff;
            #pragma unroll
            for (int j = 0; j < 32; ++j) {
                if (d[j] < best) { best = d[j]; bi = j * 64 + lane; }
            }
            uint_t ub = __float_as_uint(best);
            ub = (ub & 0x80000000u) ? ~ub : (ub | 0x80000000u);   // ascending map
            ull_t key = ((ull_t)(~ub) << 32) | (uint_t)(~bi);
            key = dpp_max_u64(key);
            uint_t wlo = (uint_t)__builtin_amdgcn_readlane((int)(uint_t)key, 63);
            bi = (int)(~wlo) & (NPTS - 1);
            if (lane == 0) g_knn[wave * KNB + r] = bi;
            if (lane == r) nmine = bi;
            int rl = bi & 63, rs = bi >> 6;
            if (lane == rl) {
                #pragma unroll
                for (int j = 0; j < 32; ++j) if (j == rs) d[j] = 1e30f;
            }
        }
    }

    // ---- score phase: lanes 0-15 each handle row (b,p,k=lane) ----
    if (lane < 16) {
        const int row = wave * KNB + lane;
        const int n = nmine & (NPTS - 1);
        const float* nb = nrm + b * 3 * NPTS;
        const float* Xb = Xa  + b * 3 * NPTS;
        const float* Yb = Ya  + b * 3 * NPTS;
        float gx, gy, gz, sq, draw, nnv;
        {
            #pragma clang fp contract(off)
            gx = xb[n]        - xb[fi];
            gy = xb[NPTS + n] - xb[NPTS + fi];
            gz = xb[2*NPTS+n] - xb[2*NPTS+fi];
            sq = gx*gx + gy*gy;
            sq = sq + gz*gz;
            draw = sqrtf(sq + 1e-10f);
            nnv = sqrtf(sq);
        }
        float dmin = draw, dmax = draw;
        #pragma unroll
        for (int m = 1; m < 16; m <<= 1) {
            dmin = fminf(dmin, __shfl_xor(dmin, m, 16));
            dmax = fmaxf(dmax, __shfl_xor(dmax, m, 16));
        }
        float dist;
        {
            #pragma clang fp contract(off)
            dist = (draw - dmin) / ((dmax - dmin) + 1e-10f);
        }
        float nx = nb[n], ny = nb[NPTS+n], nz = nb[2*NPTS+n];
        float Xx = Xb[n], Xy = Xb[NPTS+n], Xz = Xb[2*NPTS+n];
        float Yx = Yb[n], Yy = Yb[NPTS+n], Yz = Yb[2*NPTS+n];
        float g[10];
        g[0]=gx; g[1]=gy; g[2]=gz; g[3]=dist; g[4]=nx; g[5]=ny; g[6]=nz;
        {
            float vs[3][3] = {{nx,ny,nz},{Xx,Xy,Xz},{Yx,Yy,Yz}};
            #pragma unroll
            for (int a = 0; a < 3; ++a) {
                float vx=vs[a][0], vy=vs[a][1], vz=vs[a][2];
                float dot, nv;
                {
                    #pragma clang fp contract(off)
                    dot = gx*vx + gy*vy; dot = dot + gz*vz;
                    float s2 = vx*vx + vy*vy; s2 = s2 + vz*vz;
                    nv = sqrtf(s2);
                }
                float cc = dot / (nnv * nv + 1e-8f);
                cc = fminf(1.0f, fmaxf(-1.0f, cc));
                g[7+a] = acosf(cc) / 3.14159274101257324f;
            }
        }
        #pragma unroll
        for (int l = 0; l < 3; ++l) {
            float h[16];
            #pragma unroll
            for (int i = 0; i < 16; ++i) {
                float a = b1s[l][i];
                #pragma unroll
                for (int j = 0; j < 10; ++j) a += w1s[l][i][j] * g[j];
                h[i] = fmaxf(a, 0.0f);
            }
            float e[8]; float mx = -1e30f;
            #pragma unroll
            for (int m = 0; m < 8; ++m) {
                float a = b2s[l][m];
                #pragma unroll
                for (int j = 0; j < 16; ++j) a += w2s[l][m][j] * h[j];
                e[m] = a; mx = fmaxf(mx, a);
            }
            float sum = 0.0f;
            #pragma unroll
            for (int m = 0; m < 8; ++m) { e[m] = expf(e[m] - mx); sum += e[m]; }
            #pragma unroll
            for (int m = 0; m < 8; ++m)
                g_S[(size_t)l * NROWS * 8 + (size_t)row * 8 + m] = e[m] / sum;
        }
    }
}

// ---------------------------------------------------------------------------
// MFMA PAConv GEMM v8 = v7 (wave retiling) + software pipelining:
//  - B fragments PREFETCHED one K-step ahead into parity registers, issued
//    BEFORE the LDS barrier (overlap barrier wait + MFMAs). dwordx4 loads.
//  - F chunk for c0+32 prefetched at m==0 (7 K-steps of latency hiding).
//  - LDS-only barrier (vmcnt never drained in the K-loop).
// LAYER 0 also hosts small_out on blocks >= 1024.
// ---------------------------------------------------------------------------
template<int LAYER, int CIN, int COUT>
__global__ __launch_bounds__(256) void gemm_kernel(const float* __restrict__ gamma,
                                                   const float* __restrict__ beta,
                                                   float* __restrict__ dout,
                                                   const float* __restrict__ xyz,
                                                   const float* __restrict__ nrm,
                                                   const float* __restrict__ Xa,
                                                   const float* __restrict__ Ya) {
    if constexpr (LAYER == 0) {
        if (blockIdx.x >= 1024) {
            // ---- small outputs: new_xyz (fidx), new_norm/X/Y (knn[...,0]) ----
            const int g = (blockIdx.x - 1024) * 256 + threadIdx.x;   // b*512+p
            const int b = g / NPOINT, p = g % NPOINT;
            const int fi = g_fidx[g] & (NPTS - 1);
            const int n0 = g_knn[g * KNB] & (NPTS - 1);
            #pragma unroll
            for (int a = 0; a < 3; ++a) {
                dout[            (b*3 + a) * NPOINT + p] = xyz[(b*3 + a) * NPTS + fi];
                dout[12288 +     (b*3 + a) * NPOINT + p] = nrm[(b*3 + a) * NPTS + n0];
                dout[24576 +     (b*3 + a) * NPOINT + p] = Xa [(b*3 + a) * NPTS + n0];
                dout[36864 +     (b*3 + a) * NPOINT + p] = Ya [(b*3 + a) * NPTS + n0];
            }
            return;
        }
    }

    const float* __restrict__ A = (LAYER == 0) ? g_pT : (LAYER == 1) ? g_act1 : g_act2;
    float* __restrict__ O = (LAYER == 0) ? g_act1 : (LAYER == 1) ? g_act2 : dout;
    constexpr int NTT = COUT / 16;    // total col tiles
    constexpr int NTW = NTT / 4;      // col tiles per wave
    constexpr int CCM = CIN / 32;     // c-chunks
    constexpr int BOFF = (LAYER == 0) ? B0_OFF : (LAYER == 1) ? B1_OFF : B2_OFF;
    __shared__ ushort_t As[2][64][36];
    __shared__ float s_scale[(LAYER >= 1) ? CIN : 1];
    __shared__ float s_shift[(LAYER >= 1) ? CIN : 1];
    __shared__ float s_rs[(LAYER < 2) ? COUT : 1];
    __shared__ float s_rss[(LAYER < 2) ? COUT : 1];

    const int t = threadIdx.x;
    const int lane = t & 63, w = t >> 6;
    const int q = lane >> 4, nlo = lane & 15;
    const int row0 = blockIdx.x * 64;
    const int arow_i = t >> 2, acg = t & 3;

    if constexpr (LAYER >= 1) {
        const float* sb = (LAYER == 1) ? g_sums : (g_sums + 256);
        if (t < CIN) {
            float mu  = sb[t] * (1.0f / 65536.0f);
            float var = sb[CIN + t] * (1.0f / 65536.0f) - mu * mu;
            var = fmaxf(var, 0.0f);
            float sc = gamma[t] / sqrtf(var + 1e-5f);
            s_scale[t] = sc;
            s_shift[t] = beta[t] - mu * sc;
        }
        __syncthreads();
    }

    size_t arow;
    if (LAYER == 0) {
        const int row = row0 + arow_i;
        const int b = row >> 13;
        const int n = g_knn[row] & (NPTS - 1);
        arow = (size_t)(b * NPTS + n) * 64;
    } else {
        arow = (size_t)(row0 + arow_i) * CIN;
    }
    const float* Sbase = g_S + (size_t)LAYER * NROWS * 8 + (size_t)(row0 + arow_i) * 8;

    float svv[8];
    #pragma unroll
    for (int m = 0; m < 8; ++m) svv[m] = Sbase[m];

    f32x4 acc[4][NTW];
    #pragma unroll
    for (int mi = 0; mi < 4; ++mi)
        #pragma unroll
        for (int ni = 0; ni < NTW; ++ni) acc[mi][ni] = (f32x4){0.f, 0.f, 0.f, 0.f};

    const ushort_t* fbase = g_bankF + BOFF + lane * 8;

    union FragU { uint4 u4; uint2 u2[2]; short8 s; };
    FragU B[2][NTW];
    // preload B for step 0 (kc=0)
    #pragma unroll
    for (int ni = 0; ni < NTW; ++ni)
        B[0][ni].u4 = *reinterpret_cast<const uint4*>(fbase + (size_t)(w * NTW + ni) * 512);

    // preload raw F chunk 0
    float vraw[8], vnext[8];
    {
        const float* ap = A + arow + acg * 8;
        float4 fa = *reinterpret_cast<const float4*>(ap);
        float4 fb = *reinterpret_cast<const float4*>(ap + 4);
        vraw[0]=fa.x; vraw[1]=fa.y; vraw[2]=fa.z; vraw[3]=fa.w;
        vraw[4]=fb.x; vraw[5]=fb.y; vraw[6]=fb.z; vraw[7]=fb.w;
    }

    int par = 0;
    for (int cc = 0; cc < CCM; ++cc) {
        // ---- BN+relu on the (prefetched) raw chunk ----
        float v[8];
        #pragma unroll
        for (int j = 0; j < 8; ++j) {
            if constexpr (LAYER >= 1) {
                const int c = cc * 32 + acg * 8 + j;
                v[j] = fmaxf(vraw[j] * s_scale[c] + s_shift[c], 0.f);
            } else {
                v[j] = vraw[j];
            }
        }
        #pragma unroll
        for (int m = 0; m < 8; ++m) {
            // ---- stage A (sv[m]*F -> bf16) into parity buffer ----
            {
                const float sv = svv[m];
                uint_t* dst = reinterpret_cast<uint_t*>(&As[par][arow_i][acg * 8]);
                #pragma unroll
                for (int j = 0; j < 8; j += 2)
                    dst[j >> 1] = (uint_t)f2bf(sv * v[j]) | ((uint_t)f2bf(sv * v[j+1]) << 16);
            }
            // ---- prefetch next F chunk (7 steps of latency hiding) ----
            if (m == 0) {
                const int ccn = (cc + 1 < CCM) ? cc + 1 : cc;
                const float* ap = A + arow + ccn * 32 + acg * 8;
                float4 fa = *reinterpret_cast<const float4*>(ap);
                float4 fb = *reinterpret_cast<const float4*>(ap + 4);
                vnext[0]=fa.x; vnext[1]=fa.y; vnext[2]=fa.z; vnext[3]=fa.w;
                vnext[4]=fb.x; vnext[5]=fb.y; vnext[6]=fb.z; vnext[7]=fb.w;
            }
            // ---- prefetch next-step B fragments (before the barrier) ----
            {
                const int kcn = (m < 7) ? ((m + 1) * CCM + cc)
                                        : ((cc + 1 < CCM) ? (cc + 1) : 0);
                #pragma unroll
                for (int ni = 0; ni < NTW; ++ni)
                    B[(m + 1) & 1][ni].u4 = *reinterpret_cast<const uint4*>(
                        fbase + (size_t)(kcn * NTT + w * NTW + ni) * 512);
            }
            LDS_BARRIER();   // LDS-only: B loads stay in flight
            // ---- A fragments: all 4 row-tiles of the block ----
            FragU af[4];
            #pragma unroll
            for (int mi = 0; mi < 4; ++mi) {
                af[mi].u2[0] = *reinterpret_cast<const uint2*>(&As[par][mi*16 + nlo][q*8]);
                af[mi].u2[1] = *reinterpret_cast<const uint2*>(&As[par][mi*16 + nlo][q*8 + 4]);
            }
            #pragma unroll
            for (int ni = 0; ni < NTW; ++ni)
                #pragma unroll
                for (int mi = 0; mi < 4; ++mi)
                    acc[mi][ni] = __builtin_amdgcn_mfma_f32_16x16x32_bf16(
                        af[mi].s, B[m & 1][ni].s, acc[mi][ni], 0, 0, 0);
            par ^= 1;
        }
        #pragma unroll
        for (int j = 0; j < 8; ++j) vraw[j] = vnext[j];
    }

    if constexpr (LAYER == 2) {
        const int bp0 = row0 >> 4;
        #pragma unroll
        for (int mi = 0; mi < 4; ++mi) {
            const int bp = bp0 + mi;
            const int b = bp >> 9, p = bp & 511;
            #pragma unroll
            for (int ni = 0; ni < NTW; ++ni) {
                float mv = fmaxf(fmaxf(acc[mi][ni][0], acc[mi][ni][1]),
                                 fmaxf(acc[mi][ni][2], acc[mi][ni][3]));
                mv = fmaxf(mv, __shfl_xor(mv, 16));
                mv = fmaxf(mv, __shfl_xor(mv, 32));
                if (lane < 16) {
                    const int col = w * 64 + ni * 16 + nlo;
                    O[(size_t)(b * 256 + col) * NPOINT + p] = mv;
                }
            }
        }
    } else {
        #pragma unroll
        for (int mi = 0; mi < 4; ++mi)
            #pragma unroll
            for (int ni = 0; ni < NTW; ++ni)
                #pragma unroll
                for (int r2 = 0; r2 < 4; ++r2)
                    O[(size_t)(row0 + mi*16 + q*4 + r2) * COUT + w*NTW*16 + ni*16 + nlo] = acc[mi][ni][r2];
        #pragma unroll
        for (int ni = 0; ni < NTW; ++ni) {
            float s = 0.f, ss = 0.f;
            #pragma unroll
            for (int mi = 0; mi < 4; ++mi) {
                #pragma unroll
                for (int r2 = 0; r2 < 4; ++r2) {
                    float x = acc[mi][ni][r2];
                    s += x; ss += x * x;
                }
            }
            s  += __shfl_xor(s, 16);  s  += __shfl_xor(s, 32);
            ss += __shfl_xor(ss, 16); ss += __shfl_xor(ss, 32);
            if (q == 0) {
                const int c = w * NTW * 16 + ni * 16 + nlo;   // unique owner
                s_rs[c] = s;
                s_rss[c] = ss;
            }
        }
        __syncthreads();
        if (t < COUT) {
            float* sb = (LAYER == 0) ? g_sums : (g_sums + 256);
            atomicAdd(&sb[t], s_rs[t]);
            atomicAdd(&sb[COUT + t], s_rss[t]);
        }
    }
}

// ---------------------------------------------------------------------------
extern "C" void kernel_launch(void* const* d_in, const int* in_sizes, int n_in,
                              void* d_out, int out_size, void* d_ws, size_t ws_size,
                              hipStream_t stream) {
    const float* xyz    = (const float*)d_in[0];
    const float* nrm    = (const float*)d_in[1];
    const float* Xa     = (const float*)d_in[2];
    const float* Ya     = (const float*)d_in[3];
    const float* points = (const float*)d_in[4];
    const float* w1_0 = (const float*)d_in[5];  const float* b1_0 = (const float*)d_in[6];
    const float* w2_0 = (const float*)d_in[7];  const float* b2_0 = (const float*)d_in[8];
    const float* bank0 = (const float*)d_in[9];
    const float* g0 = (const float*)d_in[10];   const float* be0 = (const float*)d_in[11];
    const float* w1_1 = (const float*)d_in[12]; const float* b1_1 = (const float*)d_in[13];
    const float* w2_1 = (const float*)d_in[14]; const float* b2_1 = (const float*)d_in[15];
    const float* bank1 = (const float*)d_in[16];
    const float* g1 = (const float*)d_in[17];   const float* be1 = (const float*)d_in[18];
    const float* w1_2 = (const float*)d_in[19]; const float* b1_2 = (const float*)d_in[20];
    const float* w2_2 = (const float*)d_in[21]; const float* b2_2 = (const float*)d_in[22];
    const float* bank2 = (const float*)d_in[23];
    float* out = (float*)d_out;
    (void)d_ws; (void)ws_size; (void)in_sizes; (void)n_in; (void)out_size;

    // fps (0-7) + transpose (8-263) + zero sums (264) + bank frag conv (265-968)
    front_kernel<<<969, 512, 0, stream>>>(xyz, points, bank0, bank1, bank2);
    // KNN + geometry + all 3 score MLPs (fused per wave)
    knn_score_kernel<<<1024, 256, 0, stream>>>(xyz, nrm, Xa, Ya,
                                               w1_0, b1_0, w2_0, b2_0,
                                               w1_1, b1_1, w2_1, b2_1,
                                               w1_2, b1_2, w2_2, b2_2);
    // layer 0: gather+GEMM -> raw act1 + BN stats; blocks 1024+ = small_out
    gemm_kernel<0, 64, 64><<<1040, 256, 0, stream>>>(nullptr, nullptr, out, xyz, nrm, Xa, Ya);
    // layer 1: BN0+relu fused in staging -> raw act2 + BN stats
    gemm_kernel<1, 64, 128><<<1024, 256, 0, stream>>>(g0, be0, nullptr, nullptr, nullptr, nullptr, nullptr);
    // layer 2: BN1+relu fused in staging -> fused max-k + transpose to d_out
    gemm_kernel<2, 128, 256><<<1024, 256, 0, stream>>>(g1, be1, out + 49152, nullptr, nullptr, nullptr, nullptr);
}